// Round 1
// 570.574 us; speedup vs baseline: 1.0152x; 1.0152x over previous
//
#include <hip/hip_runtime.h>
#include <hip/hip_bf16.h>

#define DI __device__ __forceinline__

typedef short bf16x8_t __attribute__((ext_vector_type(8)));
typedef _Float16 f16x8_t __attribute__((ext_vector_type(8)));
typedef float f32x4_t __attribute__((ext_vector_type(4)));

DI unsigned short f2bf(float f) {
    unsigned u = __float_as_uint(f);
    u += 0x7fffu + ((u >> 16) & 1u);
    return (unsigned short)(u >> 16);
}
DI float bfu2f(unsigned short u) { return __uint_as_float(((unsigned)u) << 16); }
DI unsigned short f2h(float f) {
    _Float16 h = (_Float16)f;
    unsigned short u;
    __builtin_memcpy(&u, &h, 2);
    return u;
}
DI float h2f(unsigned short u) {
    _Float16 h;
    __builtin_memcpy(&h, &u, 2);
    return (float)h;
}

// ---------------------------------------------------------------------------
// Kernel 1 (fallback path): inverse channel norms for fq_feats / fs_feats.
// ---------------------------------------------------------------------------
__global__ __launch_bounds__(256) void k_norms(const float* __restrict__ fqf,
                                               const float* __restrict__ fsf,
                                               float* __restrict__ rq,
                                               float* __restrict__ rs) {
    int id = blockIdx.x * 256 + threadIdx.x;  // 0..36863
    int tensor = id / 18432;                  // block-uniform
    int r = id % 18432;
    int lb = r >> 9;
    int pp = (r & 511) * 2;
    const float* src = tensor ? fsf : fqf;
    float* dst = tensor ? rs : rq;
    const float* p = src + (size_t)lb * 524288 + pp;
    float s0 = 0.f, s1 = 0.f;
    for (int c = 0; c < 512; ++c) {
        float2 v = *(const float2*)(p + (size_t)c * 1024);
        s0 += v.x * v.x;
        s1 += v.y * v.y;
    }
    float* d = dst + lb * 1024 + pp;
    d[0] = 1.f / fmaxf(sqrtf(s0), 1e-12f);
    d[1] = 1.f / fmaxf(sqrtf(s1), 1e-12f);
}

// ---------------------------------------------------------------------------
// Kernel 1b (fast path): fused norms + pre-normalized f16 transposed tiles.
// Output layout per (lb, ptile): 16 k-step tiles of 8 KB. Tile = 512 chunks of
// 16 B; phys chunk p16 = m*4 + (q ^ ((m>>2)&3)) holds halves k=q*8..q*8+7 of
// position row m (chunk-XOR swizzle -> conflict-free ds_read_b128 frags).
// grid (8 ptile, 36 lb, 2 tensor) x 256.
// ---------------------------------------------------------------------------
__global__ __launch_bounds__(256) void k_prep(const float* __restrict__ fqf,
                                              const float* __restrict__ fsf,
                                              unsigned short* __restrict__ fqb,
                                              unsigned short* __restrict__ fsb) {
    __shared__ float T[128 * 33];   // transposed fp32 sub-tile [pos][33]
    __shared__ float red[512];
    __shared__ float invn[128];
    const int pt = blockIdx.x;
    const int lb = blockIdx.y;
    const int tz = blockIdx.z;
    const float* src = (tz ? fsf : fqf) + (size_t)lb * 524288 + pt * 128;
    unsigned short* dst = (tz ? fsb : fqb) + (((size_t)(lb * 8 + pt)) << 16);
    const int t = threadIdx.x;

    // phase A: per-position inverse channel norms (coalesced float2 stream)
    {
        const int p2 = (t & 63) * 2, cg = t >> 6;
        const float* ap = src + (((size_t)(cg * 128)) << 10) + p2;
        float s0 = 0.f, s1 = 0.f;
        for (int c = 0; c < 128; ++c) {
            float2 v = *(const float2*)(ap + ((size_t)c << 10));
            s0 += v.x * v.x;
            s1 += v.y * v.y;
        }
        red[t] = s0;
        red[256 + t] = s1;
        __syncthreads();
        if (t < 64) {
            float a0 = red[t] + red[t + 64] + red[t + 128] + red[t + 192];
            float a1 = red[256 + t] + red[320 + t] + red[384 + t] + red[448 + t];
            invn[2 * t]     = 1.f / fmaxf(sqrtf(a0), 1e-12f);
            invn[2 * t + 1] = 1.f / fmaxf(sqrtf(a1), 1e-12f);
        }
    }

    for (int ks = 0; ks < 16; ++ks) {
        __syncthreads();
        // phase B: coalesced read [32 ch][128 pos] fp32 -> LDS transposed
#pragma unroll
        for (int j = 0; j < 4; ++j) {
            int f = t + (j << 8);
            int row = f >> 5;            // channel 0..31
            int m4 = (f & 31) << 2;      // position 0..124
            float4 v = *(const float4*)(src + (((size_t)(ks * 32 + row)) << 10) + m4);
            T[(m4 + 0) * 33 + row] = v.x;
            T[(m4 + 1) * 33 + row] = v.y;
            T[(m4 + 2) * 33 + row] = v.z;
            T[(m4 + 3) * 33 + row] = v.w;
        }
        __syncthreads();
        // phase C: normalize, f16, swizzled 16B chunk writes (coalesced)
#pragma unroll
        for (int i = 0; i < 2; ++i) {
            int c = t + (i << 8);        // phys chunk 0..511
            int m = c >> 2;
            int q = (c & 3) ^ ((m >> 2) & 3);
            const float* Tp = &T[m * 33 + q * 8];
            float iv = invn[m];
            uint4 r4;
            r4.x = (unsigned)f2h(Tp[0] * iv) | ((unsigned)f2h(Tp[1] * iv) << 16);
            r4.y = (unsigned)f2h(Tp[2] * iv) | ((unsigned)f2h(Tp[3] * iv) << 16);
            r4.z = (unsigned)f2h(Tp[4] * iv) | ((unsigned)f2h(Tp[5] * iv) << 16);
            r4.w = (unsigned)f2h(Tp[6] * iv) | ((unsigned)f2h(Tp[7] * iv) << 16);
            *(uint4*)(dst + ((size_t)ks << 12) + ((size_t)c << 3)) = r4;
        }
    }
}

// ---------------------------------------------------------------------------
// Kernel 2 (fallback path, fp32 inputs): corr partials, 2-way level split.
// ---------------------------------------------------------------------------
DI void stage_tile(const float* gbase, float* lbase, int w, int lane) {
#pragma unroll
    for (int i = 0; i < 4; ++i) {
        int slot = i * 256 + w * 64 + lane;     // 16B slots 0..1023
        int r = slot >> 5;                      // row (k) 0..31
        int chp = slot & 31;                    // physical 16B chunk in row
        int msrc = ((chp * 4) - ((r >> 3) << 3)) & 127;  // un-rotated col
        __builtin_amdgcn_global_load_lds(
            (const __attribute__((address_space(1))) void*)(gbase + (size_t)r * 1024 + msrc),
            (__attribute__((address_space(3))) void*)(lbase + i * 1024 + w * 256),
            16, 0, 0);
    }
}

DI bf16x8_t build_frag(const float* base, int col, int quad) {
    const float* p = base + quad * 1024 + col;  // row quad*8, rotated col
    float f[8];
#pragma unroll
    for (int j = 0; j < 8; ++j) f[j] = p[j * 128];
    union { unsigned u[4]; bf16x8_t v; } r;
#pragma unroll
    for (int j = 0; j < 4; ++j) {
        __hip_bfloat162 h = __float22bfloat162_rn(make_float2(f[2 * j], f[2 * j + 1]));
        unsigned uu;
        __builtin_memcpy(&uu, &h, 4);
        r.u[j] = uu;
    }
    return r.v;
}

__global__ __launch_bounds__(256) void k_corr(const float* __restrict__ fqf,
                                              const float* __restrict__ fsf,
                                              const float* __restrict__ rq,
                                              const float* __restrict__ rs,
                                              unsigned short* __restrict__ P01) {
    __shared__ float As[2][4096];  // [buf][32 k x 128 m] fp32, row-rotated
    __shared__ float Bs[2][4096];
    const int b = blockIdx.z >> 1;
    const int lg = blockIdx.z & 1;
    const int q0 = blockIdx.y * 128;
    const int s0 = blockIdx.x * 128;
    const int t = threadIdx.x;
    const int w = t >> 6, lane = t & 63;
    const int wrow = w >> 1, wcol = w & 1;   // 2x2 waves of 64x64
    const int quad = lane >> 4, m16 = lane & 15;
    const int nsteps = (5 - lg) << 4;        // lg0: 80, lg1: 64

    f32x4_t zero4 = {0.f, 0.f, 0.f, 0.f};
    f32x4_t master[4][4], lvl[4][4];
#pragma unroll
    for (int i = 0; i < 4; ++i)
#pragma unroll
        for (int j = 0; j < 4; ++j) { master[i][j] = zero4; lvl[i][j] = zero4; }

    {
        const float* Ab = fqf + (size_t)(lg * 4 + b) * 524288 + q0;
        const float* Bb = fsf + (size_t)(lg * 4 + b) * 524288 + s0;
        stage_tile(Ab, &As[0][0], w, lane);
        stage_tile(Bb, &Bs[0][0], w, lane);
    }

    for (int step = 0; step < nsteps; ++step) {
        const int buf = step & 1;
        __syncthreads();
        if (step < nsteps - 1) {
            int ns = step + 1;
            int lb = (lg + 2 * (ns >> 4)) * 4 + b;
            int kk0 = (ns & 15) << 5;
            const float* Ab = fqf + (size_t)lb * 524288 + (size_t)kk0 * 1024 + q0;
            const float* Bb = fsf + (size_t)lb * 524288 + (size_t)kk0 * 1024 + s0;
            stage_tile(Ab, &As[buf ^ 1][0], w, lane);
            stage_tile(Bb, &Bs[buf ^ 1][0], w, lane);
        }
        const float* Ab = &As[buf][0];
        const float* Bb = &Bs[buf][0];
        bf16x8_t af[4], bfr[4];
#pragma unroll
        for (int i = 0; i < 4; ++i) {
            af[i]  = build_frag(Ab, ((wrow * 64 + i * 16 + m16) + quad * 8) & 127, quad);
            bfr[i] = build_frag(Bb, ((wcol * 64 + i * 16 + m16) + quad * 8) & 127, quad);
        }
#pragma unroll
        for (int mi = 0; mi < 4; ++mi)
#pragma unroll
            for (int ni = 0; ni < 4; ++ni)
                lvl[mi][ni] = __builtin_amdgcn_mfma_f32_16x16x32_bf16(
                    af[mi], bfr[ni], lvl[mi][ni], 0, 0, 0);

        if ((step & 15) == 15) {
            int lb = (lg + 2 * (step >> 4)) * 4 + b;
            const float* rqb = rq + lb * 1024 + q0 + wrow * 64;
            const float* rsb = rs + lb * 1024 + s0 + wcol * 64;
            float rq4[4][4], rsv[4];
#pragma unroll
            for (int mi = 0; mi < 4; ++mi) {
                float4 v = *(const float4*)(rqb + mi * 16 + quad * 4);
                rq4[mi][0] = v.x; rq4[mi][1] = v.y; rq4[mi][2] = v.z; rq4[mi][3] = v.w;
            }
#pragma unroll
            for (int ni = 0; ni < 4; ++ni) rsv[ni] = rsb[ni * 16 + m16];
#pragma unroll
            for (int mi = 0; mi < 4; ++mi)
#pragma unroll
                for (int ni = 0; ni < 4; ++ni) {
#pragma unroll
                    for (int e = 0; e < 4; ++e)
                        master[mi][ni][e] += fmaxf(lvl[mi][ni][e] * rq4[mi][e] * rsv[ni], 0.f);
                    lvl[mi][ni] = zero4;
                }
        }
    }

#pragma unroll
    for (int mi = 0; mi < 4; ++mi)
#pragma unroll
        for (int e = 0; e < 4; ++e) {
            int q = q0 + wrow * 64 + mi * 16 + quad * 4 + e;
            unsigned short* cp = P01 + ((((size_t)(lg * 4 + b)) * 1024 + q) << 10)
                                 + s0 + wcol * 64 + m16;
#pragma unroll
            for (int ni = 0; ni < 4; ++ni)
                cp[ni * 16] = f2h(master[mi][ni][e]);
        }
}

// ---------------------------------------------------------------------------
// Kernel 2b (fast path, f16 prenormalized tiles): corr partials.
// grid dim3(512): id&7 -> (b,lg) so each XCD owns one (b,lg) (L2 locality);
// id>>3 -> 8x8 (q,s) tile. Staging = linear global_load_lds of 8 KB tile
// images; fragments = single ds_read_b128 (chunk-XOR swizzle, ~2-way max).
// ---------------------------------------------------------------------------
__global__ __launch_bounds__(256) void k_corr2(const unsigned short* __restrict__ fqb,
                                               const unsigned short* __restrict__ fsb,
                                               unsigned short* __restrict__ P01) {
    __shared__ __align__(16) char L[2][16384];   // A 8 KB | B 8 KB per buf
    const int id = blockIdx.x;
    const int z = id & 7, local = id >> 3;       // z -> XCD-resident (b,lg)
    const int b = z >> 1, lg = z & 1;
    const int qt = local >> 3, st = local & 7;
    const int q0 = qt * 128, s0 = st * 128;
    const int t = threadIdx.x;
    const int w = t >> 6, lane = t & 63;
    const int wrow = w >> 1, wcol = w & 1;
    const int quad = lane >> 4, m16 = lane & 15;
    const int nsteps = (5 - lg) << 4;            // lg0: 80, lg1: 64

    f32x4_t zero4 = {0.f, 0.f, 0.f, 0.f};
    f32x4_t master[4][4], lvl[4][4];
#pragma unroll
    for (int i = 0; i < 4; ++i)
#pragma unroll
        for (int j = 0; j < 4; ++j) { master[i][j] = zero4; lvl[i][j] = zero4; }

    auto stage = [&](int step, int buf) {
        int g = step >> 4, ks = step & 15;
        int lb = (lg + 2 * g) * 4 + b;
        const unsigned short* Ab = fqb + ((((size_t)lb * 8 + qt) * 16 + ks) << 12);
        const unsigned short* Bb = fsb + ((((size_t)lb * 8 + st) * 16 + ks) << 12);
#pragma unroll
        for (int i = 0; i < 4; ++i) {
            int idx0 = i * 256 + w * 64;   // wave-uniform; A:0..511, B:512..1023
            int idx = idx0 + lane;
            const unsigned short* srcp = (idx0 < 512)
                ? (Ab + ((size_t)idx << 3))
                : (Bb + ((size_t)(idx - 512) << 3));
            __builtin_amdgcn_global_load_lds(
                (const __attribute__((address_space(1))) void*)srcp,
                (__attribute__((address_space(3))) void*)(&L[buf][0] + idx0 * 16),
                16, 0, 0);
        }
    };

    stage(0, 0);
    for (int step = 0; step < nsteps; ++step) {
        const int buf = step & 1;
        __syncthreads();
        if (step < nsteps - 1) stage(step + 1, buf ^ 1);
        const char* base = &L[buf][0];
        f16x8_t af[4], bfr[4];
#pragma unroll
        for (int i = 0; i < 4; ++i) {
            int m = wrow * 64 + i * 16 + m16;
            int sa = quad ^ ((m >> 2) & 3);
            af[i] = *(const f16x8_t*)(base + m * 64 + sa * 16);
            int n = wcol * 64 + i * 16 + m16;
            int sb = quad ^ ((n >> 2) & 3);
            bfr[i] = *(const f16x8_t*)(base + 8192 + n * 64 + sb * 16);
        }
#pragma unroll
        for (int mi = 0; mi < 4; ++mi)
#pragma unroll
            for (int ni = 0; ni < 4; ++ni)
                lvl[mi][ni] = __builtin_amdgcn_mfma_f32_16x16x32_f16(
                    af[mi], bfr[ni], lvl[mi][ni], 0, 0, 0);

        if ((step & 15) == 15) {   // end of a level: inputs prenormalized
#pragma unroll
            for (int mi = 0; mi < 4; ++mi)
#pragma unroll
                for (int ni = 0; ni < 4; ++ni) {
#pragma unroll
                    for (int e = 0; e < 4; ++e)
                        master[mi][ni][e] += fmaxf(lvl[mi][ni][e], 0.f);
                    lvl[mi][ni] = zero4;
                }
        }
    }

#pragma unroll
    for (int mi = 0; mi < 4; ++mi)
#pragma unroll
        for (int e = 0; e < 4; ++e) {
            int q = q0 + wrow * 64 + mi * 16 + quad * 4 + e;
            unsigned short* cp = P01 + ((((size_t)(lg * 4 + b)) * 1024 + q) << 10)
                                 + s0 + wcol * 64 + m16;
#pragma unroll
            for (int ni = 0; ni < 4; ++ni)
                cp[ni * 16] = f2h(master[mi][ni][e]);
        }
}

// ---------------------------------------------------------------------------
// Kernel 3: softmax over s. Reads 2 fp16 partials, scale 20/9, writes attn as
// padded fp16 [b][sb(32)][q][36] for MFMA staging.
// ---------------------------------------------------------------------------
__global__ __launch_bounds__(256) void k_softmax(const unsigned short* __restrict__ P01,
                                                 unsigned short* __restrict__ attn) {
    __shared__ float red[8];
    const int row = blockIdx.x;  // 0..4095
    const int b = row >> 10, q = row & 1023;
    const int t = threadIdx.x;
    const unsigned short* p0 = P01 + (((size_t)b << 20) + ((size_t)q << 10)) + t * 4;
    const unsigned short* p1 = p0 + ((size_t)4 << 20);
    uint2 a0 = *(const uint2*)p0;
    uint2 a1 = *(const uint2*)p1;
    const float SC = 20.f / 9.f;
    float v0 = (h2f(a0.x & 0xffff) + h2f(a1.x & 0xffff)) * SC;
    float v1 = (h2f(a0.x >> 16)    + h2f(a1.x >> 16)) * SC;
    float v2 = (h2f(a0.y & 0xffff) + h2f(a1.y & 0xffff)) * SC;
    float v3 = (h2f(a0.y >> 16)    + h2f(a1.y >> 16)) * SC;
    float m = fmaxf(fmaxf(v0, v1), fmaxf(v2, v3));
#pragma unroll
    for (int off = 32; off >= 1; off >>= 1) m = fmaxf(m, __shfl_down(m, off));
    const int wid = t >> 6, lane = t & 63;
    if (lane == 0) red[wid] = m;
    __syncthreads();
    m = fmaxf(fmaxf(red[0], red[1]), fmaxf(red[2], red[3]));
    float e0 = __expf(v0 - m), e1 = __expf(v1 - m);
    float e2 = __expf(v2 - m), e3 = __expf(v3 - m);
    float s = e0 + e1 + e2 + e3;
#pragma unroll
    for (int off = 32; off >= 1; off >>= 1) s += __shfl_down(s, off);
    if (lane == 0) red[4 + wid] = s;
    __syncthreads();
    s = red[4] + red[5] + red[6] + red[7];
    float inv = 1.f / s;
    unsigned short* o = attn + (size_t)((b * 32 + (t >> 3)) * 1024 + q) * 36 + (t & 7) * 4;
    uint2 r;
    r.x = (unsigned)f2h(e0 * inv) | ((unsigned)f2h(e1 * inv) << 16);
    r.y = (unsigned)f2h(e2 * inv) | ((unsigned)f2h(e3 * inv) << 16);
    *(uint2*)o = r;
}

// ---------------------------------------------------------------------------
// Kernel 4a: pack f_s fp32 [b][c][s] -> fp16 [b][sb(32)][c][36]
// ---------------------------------------------------------------------------
__global__ __launch_bounds__(256) void k_fspack(const float* __restrict__ fsi,
                                                unsigned short* __restrict__ fsp) {
    int id = blockIdx.x * 256 + threadIdx.x;  // 0..65535
    int c = id & 511, sb = (id >> 9) & 31, b = id >> 14;
    const float4* src = (const float4*)(fsi + (((size_t)(b * 512 + c)) << 10) + sb * 32);
    unsigned short* dst = fsp + (size_t)((b * 32 + sb) * 512 + c) * 36;
#pragma unroll
    for (int j = 0; j < 8; ++j) {
        float4 v = src[j];
        uint2 r;
        r.x = (unsigned)f2h(v.x) | ((unsigned)f2h(v.y) << 16);
        r.y = (unsigned)f2h(v.z) | ((unsigned)f2h(v.w) << 16);
        *(uint2*)(dst + j * 4) = r;
    }
}

// ---------------------------------------------------------------------------
// Kernel 4b (MFMA f16): att_fq[b,c,q] = sum_s attn[q,s] * f_s[c,s]
// ---------------------------------------------------------------------------
__global__ __launch_bounds__(256) void k_attfqm(const unsigned short* __restrict__ fsp,
                                                const unsigned short* __restrict__ attn,
                                                float* __restrict__ attfq) {
    __shared__ __align__(16) char L[2][14336];  // A 4608 B | B 9216 B | pad 512
    const int q0 = blockIdx.x * 128;
    const int c0 = blockIdx.y * 64;
    const int b  = blockIdx.z;
    const int t = threadIdx.x;
    const int w = t >> 6, lane = t & 63;
    const int quad = lane >> 4, m16 = lane & 15;

    f32x4_t acc[4][2];
#pragma unroll
    for (int i = 0; i < 4; ++i)
#pragma unroll
        for (int j = 0; j < 2; ++j) acc[i][j] = (f32x4_t){0.f, 0.f, 0.f, 0.f};

    auto stage = [&](int sb, int buf) {
        const char* sa = (const char*)(fsp + (size_t)((b * 32 + sb) * 512 + c0) * 36);
        const char* sbp = (const char*)(attn + (size_t)((b * 32 + sb) * 1024 + q0) * 36);
#pragma unroll
        for (int i = 0; i < 4; ++i) {
            int idx0 = i * 256 + w * 64;          // wave-uniform chunk base
            if (idx0 < 896) {                      // uniform predicate (pad reads ok)
                int idx = idx0 + lane;
                const char* src = (idx < 288) ? (sa + idx * 16) : (sbp + (idx - 288) * 16);
                __builtin_amdgcn_global_load_lds(
                    (const __attribute__((address_space(1))) void*)src,
                    (__attribute__((address_space(3))) void*)(&L[buf][0] + idx0 * 16),
                    16, 0, 0);
            }
        }
    };

    stage(0, 0);
    for (int sb = 0; sb < 32; ++sb) {
        const int buf = sb & 1;
        __syncthreads();
        if (sb < 31) stage(sb + 1, buf ^ 1);
        const char* base = &L[buf][0];
        f16x8_t af[4], bfr[2];
#pragma unroll
        for (int i = 0; i < 4; ++i) {
            const char* ap = base + (size_t)(i * 16 + m16) * 72 + quad * 16;
            union { unsigned long long d[2]; f16x8_t v; } u;
            u.d[0] = *(const unsigned long long*)ap;
            u.d[1] = *(const unsigned long long*)(ap + 8);
            af[i] = u.v;
        }
#pragma unroll
        for (int ni = 0; ni < 2; ++ni) {
            const char* bp = base + 4608 + (size_t)(w * 32 + ni * 16 + m16) * 72 + quad * 16;
            union { unsigned long long d[2]; f16x8_t v; } u;
            u.d[0] = *(const unsigned long long*)bp;
            u.d[1] = *(const unsigned long long*)(bp + 8);
            bfr[ni] = u.v;
        }
#pragma unroll
        for (int mi = 0; mi < 4; ++mi)
#pragma unroll
            for (int ni = 0; ni < 2; ++ni)
                acc[mi][ni] = __builtin_amdgcn_mfma_f32_16x16x32_f16(
                    af[mi], bfr[ni], acc[mi][ni], 0, 0, 0);
    }

#pragma unroll
    for (int mi = 0; mi < 4; ++mi)
#pragma unroll
        for (int e = 0; e < 4; ++e) {
            int c = c0 + mi * 16 + quad * 4 + e;
            float* rowp = attfq + (((size_t)(b * 512 + c)) << 10) + q0 + w * 32 + m16;
#pragma unroll
            for (int ni = 0; ni < 2; ++ni)
                rowp[ni * 16] = acc[mi][ni][e];
        }
}

// ---------------------------------------------------------------------------
// Kernel 5: fq = l2n(f_q,C) + 0.5*l2n(att_fq,C); write fq & att_fq (fp32).
// ---------------------------------------------------------------------------
__global__ __launch_bounds__(256) void k_out(const float* __restrict__ fqi,
                                             const float* __restrict__ attfq,
                                             float* __restrict__ out) {
    __shared__ float redq[256], reda[256];
    __shared__ float rnq[64], rna[64];
    const int b = blockIdx.y;
    const int p0 = blockIdx.x * 64;
    const int t = threadIdx.x;
    const int pl = t & 63, cg = t >> 6;
    const int pos = p0 + pl;
    const float* qp = fqi + (((size_t)b) << 19) + pos;
    const float* ap = attfq + (((size_t)b) << 19) + pos;
    float sq = 0.f, sa = 0.f;
    for (int c = cg * 128; c < cg * 128 + 128; ++c) {
        float q = qp[(size_t)c << 10];
        float a = ap[(size_t)c << 10];
        sq += q * q;
        sa += a * a;
    }
    redq[t] = sq; reda[t] = sa;
    __syncthreads();
    if (t < 64) {
        float q = redq[t] + redq[t + 64] + redq[t + 128] + redq[t + 192];
        float a = reda[t] + reda[t + 64] + reda[t + 128] + reda[t + 192];
        rnq[t] = 1.f / fmaxf(sqrtf(q), 1e-12f);
        rna[t] = 1.f / fmaxf(sqrtf(a), 1e-12f);
    }
    __syncthreads();
    const float RQ = rnq[pl], RA = 0.5f * rna[pl];
    float* o1 = out + (((size_t)b) << 19) + pos;
    float* o2 = o1 + 2097152;
    for (int c = cg * 128; c < cg * 128 + 128; ++c) {
        float q = qp[(size_t)c << 10];
        float a = ap[(size_t)c << 10];
        o1[(size_t)c << 10] = q * RQ + a * RA;
        o2[(size_t)c << 10] = a;
    }
}

// ---------------------------------------------------------------------------
// Kernel 6a: pack w1 fp32 [256 oc][1024 ic][9 tap] -> bf16 [tap][s][oc][36]
// ---------------------------------------------------------------------------
__global__ __launch_bounds__(256) void k_w1pack(const float* __restrict__ w1,
                                                unsigned short* __restrict__ w1p) {
    int pid = blockIdx.x * 256 + threadIdx.x;  // 0..262143 = (oc,ic)
    int oc = pid >> 10, ic = pid & 1023;
    const float* src = w1 + (size_t)pid * 9;
    float f[9];
#pragma unroll
    for (int tp = 0; tp < 9; ++tp) f[tp] = src[tp];
    int s = ic >> 5, j = ic & 31;
#pragma unroll
    for (int tp = 0; tp < 9; ++tp) {
        size_t row = ((size_t)(tp * 32 + s) * 256 + oc) * 36;
        w1p[row + j] = f2bf(f[tp]);
        if (j < 4) w1p[row + 32 + j] = 0;
    }
}

// ---------------------------------------------------------------------------
// Kernel 6b (MFMA): conv1 partials per kh-group. (verified)
// ---------------------------------------------------------------------------
__global__ __launch_bounds__(256) void k_conv1m(const float* __restrict__ fqi,
                                                const float* __restrict__ fsi,
                                                const unsigned short* __restrict__ w1p,
                                                float* __restrict__ P) {
    __shared__ __align__(16) char As[2][18432];   // [buf][256 oc][36 bf16]
    __shared__ float Bs[2][2048];                 // [buf][32 k][64 n] rotated
    const int p0 = blockIdx.x * 64;
    const int b = blockIdx.y;
    const int khg = blockIdx.z;
    const int dy = 2 * khg - 2;
    const int t = threadIdx.x;
    const int w = t >> 6, lane = t & 63;
    const int quad = lane >> 4, m16 = lane & 15;
    const int krow = t >> 3, n0 = (t & 7) * 8;   // B-staging coords
    const int brot = (krow >> 3) * 8;

    f32x4_t acc[4][4];
#pragma unroll
    for (int i = 0; i < 4; ++i)
#pragma unroll
        for (int j = 0; j < 4; ++j) acc[i][j] = (f32x4_t){0.f, 0.f, 0.f, 0.f};

    auto stageA = [&](int f, int buf) {
        int kw = f >> 5, s = f & 31;
        const char* src = (const char*)(w1p + (size_t)((khg * 3 + kw) * 32 + s) * 9216);
#pragma unroll
        for (int i = 0; i < 5; ++i) {
            int idx = i * 4 + w;
            if (idx < 18)
                __builtin_amdgcn_global_load_lds(
                    (const __attribute__((address_space(1))) void*)(src + idx * 1024 + lane * 16),
                    (__attribute__((address_space(3))) void*)(&As[buf][0] + idx * 1024),
                    16, 0, 0);
        }
    };
    auto stageB = [&](int f, int buf) {
        int kw = f >> 5, s = f & 31;
        int dx = 2 * kw - 2;
        int off = dy * 32 + dx;
        int ch = s * 32 + krow;
        const float* plane = (ch < 512)
            ? (fqi + (((size_t)(b * 512 + ch)) << 10))
            : (fsi + (((size_t)(b * 512 + ch - 512)) << 10));
        float* dst = &Bs[buf][krow * 64 + ((n0 + brot) & 63)];
#pragma unroll
        for (int j2 = 0; j2 < 4; ++j2) {
            int e0 = p0 + n0 + 2 * j2;
            int ba = e0 + off;
            int c = min(max(ba, 0), 1022);
            float2 v = *(const float2*)(plane + c);
            int y0 = e0 >> 5, xg0 = e0 & 31;
            int y1 = (e0 + 1) >> 5, xg1 = (e0 + 1) & 31;
            bool v0 = ((unsigned)(y0 + dy) < 32u) && ((unsigned)(xg0 + dx) < 32u);
            bool v1 = ((unsigned)(y1 + dy) < 32u) && ((unsigned)(xg1 + dx) < 32u);
            float2 o;
            o.x = v0 ? v.x : 0.f;
            o.y = v1 ? v.y : 0.f;
            *(float2*)(dst + 2 * j2) = o;
        }
    };

    stageA(0, 0);
    stageB(0, 0);

    for (int f = 0; f < 96; ++f) {
        const int buf = f & 1;
        __syncthreads();
        if (f < 95) {
            stageA(f + 1, buf ^ 1);
            stageB(f + 1, buf ^ 1);
        }
        bf16x8_t af[4], bfr[4];
#pragma unroll
        for (int i = 0; i < 4; ++i) {
            const char* ap = &As[buf][0] + (size_t)(w * 64 + i * 16 + m16) * 72 + quad * 16;
            union { unsigned long long d[2]; bf16x8_t v; } u;
            u.d[0] = *(const unsigned long long*)ap;
            u.d[1] = *(const unsigned long long*)(ap + 8);
            af[i] = u.v;
        }
#pragma unroll
        for (int i = 0; i < 4; ++i) {
            const float* p = &Bs[buf][0] + quad * 512 + (((i * 16 + m16) + quad * 8) & 63);
            float fv[8];
#pragma unroll
            for (int j = 0; j < 8; ++j) fv[j] = p[j * 64];
            union { unsigned u[4]; bf16x8_t v; } r;
#pragma unroll
            for (int j = 0; j < 4; ++j) {
                __hip_bfloat162 h = __float22bfloat162_rn(make_float2(fv[2 * j], fv[2 * j + 1]));
                unsigned uu;
                __builtin_memcpy(&uu, &h, 4);
                r.u[j] = uu;
            }
            bfr[i] = r.v;
        }
#pragma unroll
        for (int mi = 0; mi < 4; ++mi)
#pragma unroll
            for (int ni = 0; ni < 4; ++ni)
                acc[mi][ni] = __builtin_amdgcn_mfma_f32_16x16x32_bf16(
                    af[mi], bfr[ni], acc[mi][ni], 0, 0, 0);
    }

    float* Pb = P + (((size_t)(khg * 4 + b)) << 18) + p0;
#pragma unroll
    for (int mi = 0; mi < 4; ++mi)
#pragma unroll
        for (int e = 0; e < 4; ++e) {
            int oc = w * 64 + mi * 16 + quad * 4 + e;
            float* row = Pb + (size_t)oc * 1024 + m16;
#pragma unroll
            for (int ni = 0; ni < 4; ++ni)
                row[ni * 16] = acc[mi][ni][e];
        }
}

// ---------------------------------------------------------------------------
// Kernel 6c: x1 = relu(P0+P1+P2 + b1), stored bf16
// ---------------------------------------------------------------------------
__global__ __launch_bounds__(256) void k_c1comb(const float* __restrict__ P,
                                                const float* __restrict__ b1,
                                                unsigned short* __restrict__ x1) {
    int id = blockIdx.x * 256 + threadIdx.x;  // 4-elem index, 0..262143
    int oc = (id >> 8) & 255;
    const float4* P4 = (const float4*)P;
    float4 a = P4[id];
    float4 bv = P4[id + 262144];
    float4 c = P4[id + 524288];
    float bb = b1[oc];
    float o0 = fmaxf(a.x + bv.x + c.x + bb, 0.f);
    float o1 = fmaxf(a.y + bv.y + c.y + bb, 0.f);
    float o2 = fmaxf(a.z + bv.z + c.z + bb, 0.f);
    float o3 = fmaxf(a.w + bv.w + c.w + bb, 0.f);
    uint2 r;
    r.x = (unsigned)f2bf(o0) | ((unsigned)f2bf(o1) << 16);
    r.y = (unsigned)f2bf(o2) | ((unsigned)f2bf(o3) << 16);
    ((uint2*)x1)[id] = r;
}

// ---------------------------------------------------------------------------
// Kernel 7a: pack w2 fp32 [256 oc][256 ic][9 tap] -> bf16 [tap][s(8)][oc][36]
// ---------------------------------------------------------------------------
__global__ __launch_bounds__(256) void k_w2pack(const float* __restrict__ w2,
                                                unsigned short* __restrict__ w2p) {
    int pid = blockIdx.x * 256 + threadIdx.x;  // 0..65535 = (oc,ic)
    int oc = pid >> 8, ic = pid & 255;
    const float* src = w2 + (size_t)pid * 9;
    float f[9];
#pragma unroll
    for (int tp = 0; tp < 9; ++tp) f[tp] = src[tp];
    int s = ic >> 5, j = ic & 31;
#pragma unroll
    for (int tp = 0; tp < 9; ++tp) {
        size_t row = ((size_t)(tp * 8 + s) * 256 + oc) * 36;
        w2p[row + j] = f2bf(f[tp]);
        if (j < 4) w2p[row + 32 + j] = 0;
    }
}

// ---------------------------------------------------------------------------
// Kernel 7b (MFMA): conv2 partials per kh (x1 now bf16).
// ---------------------------------------------------------------------------
__global__ __launch_bounds__(256) void k_conv2m(const unsigned short* __restrict__ x1,
                                                const unsigned short* __restrict__ w2p,
                                                float* __restrict__ P2) {
    __shared__ __align__(16) char As[2][18432];   // [buf][256 oc][36 bf16]
    __shared__ float Bs[2][2048];                 // [buf][32 k][64 n] rotated
    const int p0 = blockIdx.x * 64;
    const int b = blockIdx.y;
    const int kh = blockIdx.z;
    const int t = threadIdx.x;
    const int w = t >> 6, lane = t & 63;
    const int quad = lane >> 4, m16 = lane & 15;
    const int krow = t >> 3, n0 = (t & 7) * 8;
    const int brot = (krow >> 3) * 8;

    f32x4_t acc[4][4];
#pragma unroll
    for (int i = 0; i < 4; ++i)
#pragma unroll
        for (int j = 0; j < 4; ++j) acc[i][j] = (f32x4_t){0.f, 0.f, 0.f, 0.f};

    auto stageA = [&](int f, int buf) {
        int kw = f >> 3, s = f & 7;
        const char* src = (const char*)(w2p + (size_t)((kh * 3 + kw) * 8 + s) * 9216);
#pragma unroll
        for (int i = 0; i < 5; ++i) {
            int idx = i * 4 + w;
            if (idx < 18)
                __builtin_amdgcn_global_load_lds(
                    (const __attribute__((address_space(1))) void*)(src + idx * 1024 + lane * 16),
                    (__attribute__((address_space(3))) void*)(&As[buf][0] + idx * 1024),
                    16, 0, 0);
        }
    };
    auto stageB = [&](int f, int buf) {
        int kw = f >> 3, s = f & 7;
        int off = kh * 32 + kw;
        int ch = s * 32 + krow;
        const unsigned short* plane = x1 + (((size_t)(b * 256 + ch)) << 10);
        float* dst = &Bs[buf][krow * 64 + ((n0 + brot) & 63)];
#pragma unroll
        for (int j2 = 0; j2 < 4; ++j2) {
            int ba = p0 + n0 + 2 * j2 + off;
            int c = min(ba, 1022);
            float2 o;
            o.x = bfu2f(plane[c]);
            o.y = bfu2f(plane[c + 1]);
            *(float2*)(dst + 2 * j2) = o;
        }
    };

    stageA(0, 0);
    stageB(0, 0);

    for (int f = 0; f < 24; ++f) {
        const int buf = f & 1;
        __syncthreads();
        if (f < 23) {
            stageA(f + 1, buf ^ 1);
            stageB(f + 1, buf ^ 1);
        }
        bf16x8_t af[4], bfr[4];
#pragma unroll
        for (int i = 0; i < 4; ++i) {
            const char* ap = &As[buf][0] + (size_t)(w * 64 + i * 16 + m16) * 72 + quad * 16;
            union { unsigned long long d[2]; bf16x8_t v; } u;
            u.d[0] = *(const unsigned long long*)ap;
            u.d[1] = *(const unsigned long long*)(ap + 8);
            af[i] = u.v;
        }
#pragma unroll
        for (int i = 0; i < 4; ++i) {
            const float* p = &Bs[buf][0] + quad * 512 + (((i * 16 + m16) + quad * 8) & 63);
            float fv[8];
#pragma unroll
            for (int j = 0; j < 8; ++j) fv[j] = p[j * 64];
            union { unsigned u[4]; bf16x8_t v; } r;
#pragma unroll
            for (int j = 0; j < 4; ++j) {
                __hip_bfloat162 h = __float22bfloat162_rn(make_float2(fv[2 * j], fv[2 * j + 1]));
                unsigned uu;
                __builtin_memcpy(&uu, &h, 4);
                r.u[j] = uu;
            }
            bfr[i] = r.v;
        }
#pragma unroll
        for (int mi = 0; mi < 4; ++mi)
#pragma unroll
            for (int ni = 0; ni < 4; ++ni)
                acc[mi][ni] = __builtin_amdgcn_mfma_f32_16x16x32_bf16(
                    af[mi], bfr[ni], acc[mi][ni], 0, 0, 0);
    }

    float* Pb = P2 + (((size_t)(kh * 4 + b)) << 18) + p0;
#pragma unroll
    for (int mi = 0; mi < 4; ++mi)
#pragma unroll
        for (int e = 0; e < 4; ++e) {
            int oc = w * 64 + mi * 16 + quad * 4 + e;
            float* row = Pb + (size_t)oc * 1024 + m16;
#pragma unroll
            for (int ni = 0; ni < 4; ++ni)
                row[ni * 16] = acc[mi][ni][e];
        }
}

// ---------------------------------------------------------------------------
// Kernel 7c: combine conv2 partials + bias, then 3x3/3 maxpool -> xp[4][256][100]
// ---------------------------------------------------------------------------
__global__ __launch_bounds__(256) void k_c2pool(const float* __restrict__ P2,
                                                const float* __restrict__ b2,
                                                float* __restrict__ xp) {
    int id = blockIdx.x * 256 + threadIdx.x;  // 0..102399
    int px = id % 10;
    int tmp = id / 10;
    int py = tmp % 10;
    int ch = tmp / 10;          // b*256 + oc
    int b = ch >> 8, oc = ch & 255;
    float bb = b2[oc];
    const float* base0 = P2 + (((size_t)(0 * 4 + b)) << 18) + (size_t)oc * 1024;
    const float* base1 = P2 + (((size_t)(1 * 4 + b)) << 18) + (size_t)oc * 1024;
    const float* base2 = P2 + (((size_t)(2 * 4 + b)) << 18) + (size_t)oc * 1024;
    float m = -3.4e38f;
#pragma unroll
    for (int dy = 0; dy < 3; ++dy)
#pragma unroll
        for (int dx = 0; dx < 3; ++dx) {
            int pos = (3 * py + dy) * 32 + 3 * px + dx;
            float v = base0[pos] + base1[pos] + base2[pos] + bb;
            m = fmaxf(m, v);
        }
    xp[id] = m;
}

// ---------------------------------------------------------------------------
// Kernel 9: conv3 (256ch, 10x10 -> 8x8) + spatial mean + b3 -> weight[1,B]
// ---------------------------------------------------------------------------
__global__ __launch_bounds__(256) void k_conv3(const float* __restrict__ xp,
                                               const float* __restrict__ w3,
                                               const float* __restrict__ b3,
                                               float* __restrict__ out) {
    __shared__ float s[256];
    int b = blockIdx.x, t = threadIdx.x;
    int pos = t & 63, qi = t >> 6;
    int y = pos >> 3, x = pos & 7;
    float acc = 0.f;
    for (int ic = qi * 64; ic < qi * 64 + 64; ++ic) {
        const float* ip = xp + ((size_t)(b * 256 + ic)) * 100 + y * 10 + x;
#pragma unroll
        for (int kh = 0; kh < 3; ++kh)
#pragma unroll
            for (int kw = 0; kw < 3; ++kw)
                acc = fmaf(w3[ic * 9 + kh * 3 + kw], ip[kh * 10 + kw], acc);
    }
    s[t] = acc;
    __syncthreads();
    if (t < 64) {
        float v = s[t] + s[t + 64] + s[t + 128] + s[t + 192];
#pragma unroll
        for (int off = 32; off >= 1; off >>= 1) v += __shfl_down(v, off);
        if (t == 0) out[4194304 + b] = v * (1.f / 64.f) + b3[0];
    }
}

// ---------------------------------------------------------------------------
extern "C" void kernel_launch(void* const* d_in, const int* in_sizes, int n_in,
                              void* d_out, int out_size, void* d_ws, size_t ws_size,
                              hipStream_t stream) {
    (void)in_sizes; (void)n_in; (void)out_size;
    const float* fqf = (const float*)d_in[0];  // fq_feats [9,4,512,32,32]
    const float* fsf = (const float*)d_in[1];  // fs_feats
    const float* fqi = (const float*)d_in[2];  // f_q [4,512,32,32]
    const float* fsi = (const float*)d_in[3];  // f_s
    const float* w1  = (const float*)d_in[4];
    const float* b1  = (const float*)d_in[5];
    const float* w2  = (const float*)d_in[6];
    const float* b2  = (const float*)d_in[7];
    const float* w3  = (const float*)d_in[8];
    const float* b3  = (const float*)d_in[9];
    float* out = (float*)d_out;

    float* W = (float*)d_ws;
    // [0 .. 4,194,304) f32:  P01 fp16 corr partials (8.4M ush); also aliased by
    //   conv1 P (3.1M f32, pre-corr), attfq fp32 (2.1M, post-softmax),
    //   conv2 P2 (3.1M f32, post-k_out)
    unsigned short* P01u = (unsigned short*)W;
    float* P     = W;
    float* attfq = W;
    float* P2    = W;
    // [4,194,304 .. 6,553,600): attn fp16 padded (4.7M ush); aliased by w1p
    //   (1.33M f32, dead after conv1m), rq/rs (dead after k_corr), w2p (post-attn)
    unsigned short* attn = (unsigned short*)(W + 4194304);
    unsigned short* w1p  = (unsigned short*)(W + 4194304);
    float* rq = W + 5521408;
    float* rs = W + 5558272;
    unsigned short* w2p  = (unsigned short*)(W + 4194304);
    // [6,553,600 .. 7,733,248): fs fp16 padded (2.36M ush)
    unsigned short* fsp = (unsigned short*)(W + 6553600);
    // [7,733,248 .. 8,257,536): x1 bf16 (1.05M ush)
    unsigned short* x1 = (unsigned short*)(W + 7733248);
    // [8,257,536 .. 8,359,936): xp fp32  (base total 33.4 MB)
    float* xp = W + 8257536;
    // fast-path only: prenormalized f16 tiles, 2 x 37.75 MB at the tail
    // [8,359,936 .. 17,797,120): fqb; [17,797,120 .. 27,234,304): fsb
    unsigned short* fqb = (unsigned short*)(W + 8359936);
    unsigned short* fsb = (unsigned short*)(W + 17797120);
    const bool big_ws = ws_size >= 108937216ULL;  // 27,234,304 floats

    // conv1 phase (scratch in P01/attn regions, dead before k_corr/softmax)
    hipLaunchKernelGGL(k_w1pack,  dim3(1024),      dim3(256), 0, stream, w1, w1p);
    hipLaunchKernelGGL(k_conv1m,  dim3(16, 4, 3),  dim3(256), 0, stream, fqi, fsi, w1p, P);
    hipLaunchKernelGGL(k_c1comb,  dim3(1024),      dim3(256), 0, stream, P, b1, x1);
    hipLaunchKernelGGL(k_fspack,  dim3(256),       dim3(256), 0, stream, fsi, fsp);
    // attention path
    if (big_ws) {
        hipLaunchKernelGGL(k_prep,  dim3(8, 36, 2), dim3(256), 0, stream, fqf, fsf, fqb, fsb);
        hipLaunchKernelGGL(k_corr2, dim3(512),      dim3(256), 0, stream, fqb, fsb, P01u);
    } else {
        hipLaunchKernelGGL(k_norms, dim3(144),      dim3(256), 0, stream, fqf, fsf, rq, rs);
        hipLaunchKernelGGL(k_corr,  dim3(8, 8, 8),  dim3(256), 0, stream, fqf, fsf, rq, rs, P01u);
    }
    hipLaunchKernelGGL(k_softmax, dim3(4096),      dim3(256), 0, stream, P01u, attn);
    hipLaunchKernelGGL(k_attfqm,  dim3(8, 8, 4),   dim3(256), 0, stream, fsp, attn, attfq);
    hipLaunchKernelGGL(k_out,     dim3(16, 4),     dim3(256), 0, stream, fqi, attfq, out);
    // conv tail (scratch reuses attention regions, dead after k_out)
    hipLaunchKernelGGL(k_w2pack,  dim3(256),       dim3(256), 0, stream, w2, w2p);
    hipLaunchKernelGGL(k_conv2m,  dim3(16, 4, 3),  dim3(256), 0, stream, x1, w2p, P2);
    hipLaunchKernelGGL(k_c2pool,  dim3(400),       dim3(256), 0, stream, P2, b2, xp);
    hipLaunchKernelGGL(k_conv3,   dim3(4),         dim3(256), 0, stream, xp, w3, b3, out);
}

// Round 2
// 501.059 us; speedup vs baseline: 1.1561x; 1.1387x over previous
//
#include <hip/hip_runtime.h>
#include <hip/hip_bf16.h>

#define DI __device__ __forceinline__

typedef short bf16x8_t __attribute__((ext_vector_type(8)));
typedef _Float16 f16x8_t __attribute__((ext_vector_type(8)));
typedef float f32x4_t __attribute__((ext_vector_type(4)));

DI unsigned short f2bf(float f) {
    unsigned u = __float_as_uint(f);
    u += 0x7fffu + ((u >> 16) & 1u);
    return (unsigned short)(u >> 16);
}
DI float bfu2f(unsigned short u) { return __uint_as_float(((unsigned)u) << 16); }
DI unsigned short f2h(float f) {
    _Float16 h = (_Float16)f;
    unsigned short u;
    __builtin_memcpy(&u, &h, 2);
    return u;
}
DI float h2f(unsigned short u) {
    _Float16 h;
    __builtin_memcpy(&h, &u, 2);
    return (float)h;
}

// ---------------------------------------------------------------------------
// Kernel 1b: fused norms + pre-normalized f16 transposed tiles.
// Output layout per (lb, ptile): 16 k-step tiles of 8 KB. Tile = 512 chunks of
// 16 B; phys chunk = m*4 + (q ^ ((m>>2)&3)) holds halves k=q*8..q*8+7 of
// position row m (chunk-XOR swizzle -> conflict-free ds_read_b128 frags).
// grid (8 ptile, 36 lb, 2 tensor) x 256.
// ---------------------------------------------------------------------------
__global__ __launch_bounds__(256) void k_prep(const float* __restrict__ fqf,
                                              const float* __restrict__ fsf,
                                              unsigned short* __restrict__ fqb,
                                              unsigned short* __restrict__ fsb) {
    __shared__ float T[128 * 33];   // transposed fp32 sub-tile [pos][33]
    __shared__ float red[512];
    __shared__ float invn[128];
    const int pt = blockIdx.x;
    const int lb = blockIdx.y;
    const int tz = blockIdx.z;
    const float* src = (tz ? fsf : fqf) + (size_t)lb * 524288 + pt * 128;
    unsigned short* dst = (tz ? fsb : fqb) + (((size_t)(lb * 8 + pt)) << 16);
    const int t = threadIdx.x;

    // phase A: per-position inverse channel norms (coalesced float2 stream)
    {
        const int p2 = (t & 63) * 2, cg = t >> 6;
        const float* ap = src + (((size_t)(cg * 128)) << 10) + p2;
        float s0 = 0.f, s1 = 0.f;
        for (int c = 0; c < 128; ++c) {
            float2 v = *(const float2*)(ap + ((size_t)c << 10));
            s0 += v.x * v.x;
            s1 += v.y * v.y;
        }
        red[t] = s0;
        red[256 + t] = s1;
        __syncthreads();
        if (t < 64) {
            float a0 = red[t] + red[t + 64] + red[t + 128] + red[t + 192];
            float a1 = red[256 + t] + red[320 + t] + red[384 + t] + red[448 + t];
            invn[2 * t]     = 1.f / fmaxf(sqrtf(a0), 1e-12f);
            invn[2 * t + 1] = 1.f / fmaxf(sqrtf(a1), 1e-12f);
        }
    }

    for (int ks = 0; ks < 16; ++ks) {
        __syncthreads();
        // phase B: coalesced read [32 ch][128 pos] fp32 -> LDS transposed
#pragma unroll
        for (int j = 0; j < 4; ++j) {
            int f = t + (j << 8);
            int row = f >> 5;            // channel 0..31
            int m4 = (f & 31) << 2;      // position 0..124
            float4 v = *(const float4*)(src + (((size_t)(ks * 32 + row)) << 10) + m4);
            T[(m4 + 0) * 33 + row] = v.x;
            T[(m4 + 1) * 33 + row] = v.y;
            T[(m4 + 2) * 33 + row] = v.z;
            T[(m4 + 3) * 33 + row] = v.w;
        }
        __syncthreads();
        // phase C: normalize, f16, swizzled 16B chunk writes (coalesced)
#pragma unroll
        for (int i = 0; i < 2; ++i) {
            int c = t + (i << 8);        // phys chunk 0..511
            int m = c >> 2;
            int q = (c & 3) ^ ((m >> 2) & 3);
            const float* Tp = &T[m * 33 + q * 8];
            float iv = invn[m];
            uint4 r4;
            r4.x = (unsigned)f2h(Tp[0] * iv) | ((unsigned)f2h(Tp[1] * iv) << 16);
            r4.y = (unsigned)f2h(Tp[2] * iv) | ((unsigned)f2h(Tp[3] * iv) << 16);
            r4.z = (unsigned)f2h(Tp[4] * iv) | ((unsigned)f2h(Tp[5] * iv) << 16);
            r4.w = (unsigned)f2h(Tp[6] * iv) | ((unsigned)f2h(Tp[7] * iv) << 16);
            *(uint4*)(dst + ((size_t)ks << 12) + ((size_t)c << 3)) = r4;
        }
    }
}

// ---------------------------------------------------------------------------
// Kernel 2b (f16 prenormalized tiles): corr partials, 2-way level split.
// grid dim3(512): id&7 -> (b,lg) so each XCD owns one (b,lg) (L2 locality);
// id>>3 -> 8x8 (q,s) tile. Staging = linear global_load_lds of 8 KB tile
// images; fragments = single ds_read_b128 (chunk-XOR swizzle).
// ---------------------------------------------------------------------------
__global__ __launch_bounds__(256) void k_corr2(const unsigned short* __restrict__ fqb,
                                               const unsigned short* __restrict__ fsb,
                                               unsigned short* __restrict__ P01) {
    __shared__ __align__(16) char L[2][16384];   // A 8 KB | B 8 KB per buf
    const int id = blockIdx.x;
    const int z = id & 7, local = id >> 3;       // z -> XCD-resident (b,lg)
    const int b = z >> 1, lg = z & 1;
    const int qt = local >> 3, st = local & 7;
    const int q0 = qt * 128, s0 = st * 128;
    const int t = threadIdx.x;
    const int w = t >> 6, lane = t & 63;
    const int wrow = w >> 1, wcol = w & 1;
    const int quad = lane >> 4, m16 = lane & 15;
    const int nsteps = (5 - lg) << 4;            // lg0: 80, lg1: 64

    f32x4_t zero4 = {0.f, 0.f, 0.f, 0.f};
    f32x4_t master[4][4], lvl[4][4];
#pragma unroll
    for (int i = 0; i < 4; ++i)
#pragma unroll
        for (int j = 0; j < 4; ++j) { master[i][j] = zero4; lvl[i][j] = zero4; }

    auto stage = [&](int step, int buf) {
        int g = step >> 4, ks = step & 15;
        int lb = (lg + 2 * g) * 4 + b;
        const unsigned short* Ab = fqb + ((((size_t)lb * 8 + qt) * 16 + ks) << 12);
        const unsigned short* Bb = fsb + ((((size_t)lb * 8 + st) * 16 + ks) << 12);
#pragma unroll
        for (int i = 0; i < 4; ++i) {
            int idx0 = i * 256 + w * 64;   // wave-uniform; A:0..511, B:512..1023
            int idx = idx0 + lane;
            const unsigned short* srcp = (idx0 < 512)
                ? (Ab + ((size_t)idx << 3))
                : (Bb + ((size_t)(idx - 512) << 3));
            __builtin_amdgcn_global_load_lds(
                (const __attribute__((address_space(1))) void*)srcp,
                (__attribute__((address_space(3))) void*)(&L[buf][0] + idx0 * 16),
                16, 0, 0);
        }
    };

    stage(0, 0);
    for (int step = 0; step < nsteps; ++step) {
        const int buf = step & 1;
        __syncthreads();
        if (step < nsteps - 1) stage(step + 1, buf ^ 1);
        const char* base = &L[buf][0];
        f16x8_t af[4], bfr[4];
#pragma unroll
        for (int i = 0; i < 4; ++i) {
            int m = wrow * 64 + i * 16 + m16;
            int sa = quad ^ ((m >> 2) & 3);
            af[i] = *(const f16x8_t*)(base + m * 64 + sa * 16);
            int n = wcol * 64 + i * 16 + m16;
            int sb = quad ^ ((n >> 2) & 3);
            bfr[i] = *(const f16x8_t*)(base + 8192 + n * 64 + sb * 16);
        }
#pragma unroll
        for (int mi = 0; mi < 4; ++mi)
#pragma unroll
            for (int ni = 0; ni < 4; ++ni)
                lvl[mi][ni] = __builtin_amdgcn_mfma_f32_16x16x32_f16(
                    af[mi], bfr[ni], lvl[mi][ni], 0, 0, 0);

        if ((step & 15) == 15) {   // end of a level: inputs prenormalized
#pragma unroll
            for (int mi = 0; mi < 4; ++mi)
#pragma unroll
                for (int ni = 0; ni < 4; ++ni) {
#pragma unroll
                    for (int e = 0; e < 4; ++e)
                        master[mi][ni][e] += fmaxf(lvl[mi][ni][e], 0.f);
                    lvl[mi][ni] = zero4;
                }
        }
    }

#pragma unroll
    for (int mi = 0; mi < 4; ++mi)
#pragma unroll
        for (int e = 0; e < 4; ++e) {
            int q = q0 + wrow * 64 + mi * 16 + quad * 4 + e;
            unsigned short* cp = P01 + ((((size_t)(lg * 4 + b)) * 1024 + q) << 10)
                                 + s0 + wcol * 64 + m16;
#pragma unroll
            for (int ni = 0; ni < 4; ++ni)
                cp[ni * 16] = f2h(master[mi][ni][e]);
        }
}

// ---------------------------------------------------------------------------
// Kernel 3: softmax over s. Reads 2 fp16 partials, scale 20/9, writes attn as
// padded fp16 [b][sb(32)][q][36] for MFMA staging.
// ---------------------------------------------------------------------------
__global__ __launch_bounds__(256) void k_softmax(const unsigned short* __restrict__ P01,
                                                 unsigned short* __restrict__ attn) {
    __shared__ float red[8];
    const int row = blockIdx.x;  // 0..4095
    const int b = row >> 10, q = row & 1023;
    const int t = threadIdx.x;
    const unsigned short* p0 = P01 + (((size_t)b << 20) + ((size_t)q << 10)) + t * 4;
    const unsigned short* p1 = p0 + ((size_t)4 << 20);
    uint2 a0 = *(const uint2*)p0;
    uint2 a1 = *(const uint2*)p1;
    const float SC = 20.f / 9.f;
    float v0 = (h2f(a0.x & 0xffff) + h2f(a1.x & 0xffff)) * SC;
    float v1 = (h2f(a0.x >> 16)    + h2f(a1.x >> 16)) * SC;
    float v2 = (h2f(a0.y & 0xffff) + h2f(a1.y & 0xffff)) * SC;
    float v3 = (h2f(a0.y >> 16)    + h2f(a1.y >> 16)) * SC;
    float m = fmaxf(fmaxf(v0, v1), fmaxf(v2, v3));
#pragma unroll
    for (int off = 32; off >= 1; off >>= 1) m = fmaxf(m, __shfl_down(m, off));
    const int wid = t >> 6, lane = t & 63;
    if (lane == 0) red[wid] = m;
    __syncthreads();
    m = fmaxf(fmaxf(red[0], red[1]), fmaxf(red[2], red[3]));
    float e0 = __expf(v0 - m), e1 = __expf(v1 - m);
    float e2 = __expf(v2 - m), e3 = __expf(v3 - m);
    float s = e0 + e1 + e2 + e3;
#pragma unroll
    for (int off = 32; off >= 1; off >>= 1) s += __shfl_down(s, off);
    if (lane == 0) red[4 + wid] = s;
    __syncthreads();
    s = red[4] + red[5] + red[6] + red[7];
    float inv = 1.f / s;
    unsigned short* o = attn + (size_t)((b * 32 + (t >> 3)) * 1024 + q) * 36 + (t & 7) * 4;
    uint2 r;
    r.x = (unsigned)f2h(e0 * inv) | ((unsigned)f2h(e1 * inv) << 16);
    r.y = (unsigned)f2h(e2 * inv) | ((unsigned)f2h(e3 * inv) << 16);
    *(uint2*)o = r;
}

// ---------------------------------------------------------------------------
// Kernel 4a: pack f_s fp32 [b][c][s] -> fp16 [b][sb(32)][c][36]
// ---------------------------------------------------------------------------
__global__ __launch_bounds__(256) void k_fspack(const float* __restrict__ fsi,
                                                unsigned short* __restrict__ fsp) {
    int id = blockIdx.x * 256 + threadIdx.x;  // 0..65535
    int c = id & 511, sb = (id >> 9) & 31, b = id >> 14;
    const float4* src = (const float4*)(fsi + (((size_t)(b * 512 + c)) << 10) + sb * 32);
    unsigned short* dst = fsp + (size_t)((b * 32 + sb) * 512 + c) * 36;
#pragma unroll
    for (int j = 0; j < 8; ++j) {
        float4 v = src[j];
        uint2 r;
        r.x = (unsigned)f2h(v.x) | ((unsigned)f2h(v.y) << 16);
        r.y = (unsigned)f2h(v.z) | ((unsigned)f2h(v.w) << 16);
        *(uint2*)(dst + j * 4) = r;
    }
}

// ---------------------------------------------------------------------------
// Kernel 4b (MFMA f16): att_fq[b,c,q] = sum_s attn[q,s] * f_s[c,s]
// ---------------------------------------------------------------------------
__global__ __launch_bounds__(256) void k_attfqm(const unsigned short* __restrict__ fsp,
                                                const unsigned short* __restrict__ attn,
                                                float* __restrict__ attfq) {
    __shared__ __align__(16) char L[2][14336];  // A 4608 B | B 9216 B | pad 512
    const int q0 = blockIdx.x * 128;
    const int c0 = blockIdx.y * 64;
    const int b  = blockIdx.z;
    const int t = threadIdx.x;
    const int w = t >> 6, lane = t & 63;
    const int quad = lane >> 4, m16 = lane & 15;

    f32x4_t acc[4][2];
#pragma unroll
    for (int i = 0; i < 4; ++i)
#pragma unroll
        for (int j = 0; j < 2; ++j) acc[i][j] = (f32x4_t){0.f, 0.f, 0.f, 0.f};

    auto stage = [&](int sb, int buf) {
        const char* sa = (const char*)(fsp + (size_t)((b * 32 + sb) * 512 + c0) * 36);
        const char* sbp = (const char*)(attn + (size_t)((b * 32 + sb) * 1024 + q0) * 36);
#pragma unroll
        for (int i = 0; i < 4; ++i) {
            int idx0 = i * 256 + w * 64;          // wave-uniform chunk base
            if (idx0 < 896) {                      // uniform predicate (pad reads ok)
                int idx = idx0 + lane;
                const char* src = (idx < 288) ? (sa + idx * 16) : (sbp + (idx - 288) * 16);
                __builtin_amdgcn_global_load_lds(
                    (const __attribute__((address_space(1))) void*)src,
                    (__attribute__((address_space(3))) void*)(&L[buf][0] + idx0 * 16),
                    16, 0, 0);
            }
        }
    };

    stage(0, 0);
    for (int sb = 0; sb < 32; ++sb) {
        const int buf = sb & 1;
        __syncthreads();
        if (sb < 31) stage(sb + 1, buf ^ 1);
        const char* base = &L[buf][0];
        f16x8_t af[4], bfr[2];
#pragma unroll
        for (int i = 0; i < 4; ++i) {
            const char* ap = base + (size_t)(i * 16 + m16) * 72 + quad * 16;
            union { unsigned long long d[2]; f16x8_t v; } u;
            u.d[0] = *(const unsigned long long*)ap;
            u.d[1] = *(const unsigned long long*)(ap + 8);
            af[i] = u.v;
        }
#pragma unroll
        for (int ni = 0; ni < 2; ++ni) {
            const char* bp = base + 4608 + (size_t)(w * 32 + ni * 16 + m16) * 72 + quad * 16;
            union { unsigned long long d[2]; f16x8_t v; } u;
            u.d[0] = *(const unsigned long long*)bp;
            u.d[1] = *(const unsigned long long*)(bp + 8);
            bfr[ni] = u.v;
        }
#pragma unroll
        for (int mi = 0; mi < 4; ++mi)
#pragma unroll
            for (int ni = 0; ni < 2; ++ni)
                acc[mi][ni] = __builtin_amdgcn_mfma_f32_16x16x32_f16(
                    af[mi], bfr[ni], acc[mi][ni], 0, 0, 0);
    }

#pragma unroll
    for (int mi = 0; mi < 4; ++mi)
#pragma unroll
        for (int e = 0; e < 4; ++e) {
            int c = c0 + mi * 16 + quad * 4 + e;
            float* rowp = attfq + (((size_t)(b * 512 + c)) << 10) + q0 + w * 32 + m16;
#pragma unroll
            for (int ni = 0; ni < 2; ++ni)
                rowp[ni * 16] = acc[mi][ni][e];
        }
}

// ---------------------------------------------------------------------------
// Kernel 5: fq = l2n(f_q,C) + 0.5*l2n(att_fq,C); write fq & att_fq (fp32).
// ---------------------------------------------------------------------------
__global__ __launch_bounds__(256) void k_out(const float* __restrict__ fqi,
                                             const float* __restrict__ attfq,
                                             float* __restrict__ out) {
    __shared__ float redq[256], reda[256];
    __shared__ float rnq[64], rna[64];
    const int b = blockIdx.y;
    const int p0 = blockIdx.x * 64;
    const int t = threadIdx.x;
    const int pl = t & 63, cg = t >> 6;
    const int pos = p0 + pl;
    const float* qp = fqi + (((size_t)b) << 19) + pos;
    const float* ap = attfq + (((size_t)b) << 19) + pos;
    float sq = 0.f, sa = 0.f;
    for (int c = cg * 128; c < cg * 128 + 128; ++c) {
        float q = qp[(size_t)c << 10];
        float a = ap[(size_t)c << 10];
        sq += q * q;
        sa += a * a;
    }
    redq[t] = sq; reda[t] = sa;
    __syncthreads();
    if (t < 64) {
        float q = redq[t] + redq[t + 64] + redq[t + 128] + redq[t + 192];
        float a = reda[t] + reda[t + 64] + reda[t + 128] + reda[t + 192];
        rnq[t] = 1.f / fmaxf(sqrtf(q), 1e-12f);
        rna[t] = 1.f / fmaxf(sqrtf(a), 1e-12f);
    }
    __syncthreads();
    const float RQ = rnq[pl], RA = 0.5f * rna[pl];
    float* o1 = out + (((size_t)b) << 19) + pos;
    float* o2 = o1 + 2097152;
    for (int c = cg * 128; c < cg * 128 + 128; ++c) {
        float q = qp[(size_t)c << 10];
        float a = ap[(size_t)c << 10];
        o1[(size_t)c << 10] = q * RQ + a * RA;
        o2[(size_t)c << 10] = a;
    }
}

// ---------------------------------------------------------------------------
// Kernel 6a: pack w1 fp32 [256 oc][1024 ic][9 tap] -> bf16 [tap][s(32)][oc][40]
// ---------------------------------------------------------------------------
__global__ __launch_bounds__(256) void k_w1pack(const float* __restrict__ w1,
                                                unsigned short* __restrict__ w1p) {
    int pid = blockIdx.x * 256 + threadIdx.x;  // 0..262143 = (oc,ic)
    int oc = pid >> 10, ic = pid & 1023;
    const float* src = w1 + (size_t)pid * 9;
    float f[9];
#pragma unroll
    for (int tp = 0; tp < 9; ++tp) f[tp] = src[tp];
    int s = ic >> 5, j = ic & 31;
#pragma unroll
    for (int tp = 0; tp < 9; ++tp) {
        size_t row = ((size_t)(tp * 32 + s) * 256 + oc) * 40;
        w1p[row + j] = f2bf(f[tp]);
        if (j < 8) w1p[row + 32 + j] = 0;
    }
}

// ---------------------------------------------------------------------------
// Kernel 6b (MFMA): conv1 partials, one tap per block-z (9-way K split).
// grid (16 pos-tiles, 4 b, 9 tap). 32 K-steps of BK=32 channels.
// B staged bf16 in MFMA fragment layout (chunk-XOR swizzle): thread owns one
// spatial position n + 8 channels -> coalesced loads, 1 ds_write_b128; frag
// read = 1 ds_read_b128. Boundary mask is per-thread constant.
// ---------------------------------------------------------------------------
__global__ __launch_bounds__(256) void k_conv1m(const float* __restrict__ fqi,
                                                const float* __restrict__ fsi,
                                                const unsigned short* __restrict__ w1p,
                                                float* __restrict__ P) {
    __shared__ __align__(16) char As[2][20480];   // [buf][256 oc][40 bf16]
    __shared__ __align__(16) char Bs[2][4096];    // [buf][64 n][32 k] bf16 swz
    const int p0 = blockIdx.x * 64;
    const int b = blockIdx.y;
    const int tap = blockIdx.z;                   // kh*3+kw
    const int dy = 2 * (tap / 3) - 2;
    const int dx = 2 * (tap % 3) - 2;
    const int t = threadIdx.x;
    const int w = t >> 6, lane = t & 63;
    const int quad = lane >> 4, m16 = lane & 15;
    // B-staging per-thread constants
    const int bn = t & 63, kg = t >> 6;
    const int e0 = p0 + bn;
    const bool valid = ((unsigned)((e0 >> 5) + dy) < 32u) &&
                       ((unsigned)((e0 & 31) + dx) < 32u);
    const int cidx = min(max(e0 + dy * 32 + dx, 0), 1023);
    const int bchunk = (bn * 4 + (kg ^ (bn & 3))) * 16;

    f32x4_t acc[4][4];
#pragma unroll
    for (int i = 0; i < 4; ++i)
#pragma unroll
        for (int j = 0; j < 4; ++j) acc[i][j] = (f32x4_t){0.f, 0.f, 0.f, 0.f};

    auto stageA = [&](int s, int buf) {
        const char* src = (const char*)(w1p + (size_t)(tap * 32 + s) * 10240);
#pragma unroll
        for (int i = 0; i < 5; ++i) {
            int idx = i * 4 + w;
            __builtin_amdgcn_global_load_lds(
                (const __attribute__((address_space(1))) void*)(src + idx * 1024 + lane * 16),
                (__attribute__((address_space(3))) void*)(&As[buf][0] + idx * 1024),
                16, 0, 0);
        }
    };
    auto stageB = [&](int s, int buf) {
        int ch = s * 32 + kg * 8;                 // 8-ch group never straddles 512
        const float* plane = (ch < 512)
            ? (fqi + (((size_t)(b * 512 + ch)) << 10))
            : (fsi + (((size_t)(b * 512 + ch - 512)) << 10));
        float f[8];
#pragma unroll
        for (int j = 0; j < 8; ++j) {
            float v = plane[((size_t)j << 10) + cidx];
            f[j] = valid ? v : 0.f;
        }
        uint4 r4;
        r4.x = (unsigned)f2bf(f[0]) | ((unsigned)f2bf(f[1]) << 16);
        r4.y = (unsigned)f2bf(f[2]) | ((unsigned)f2bf(f[3]) << 16);
        r4.z = (unsigned)f2bf(f[4]) | ((unsigned)f2bf(f[5]) << 16);
        r4.w = (unsigned)f2bf(f[6]) | ((unsigned)f2bf(f[7]) << 16);
        *(uint4*)(&Bs[buf][bchunk]) = r4;
    };

    stageA(0, 0);
    stageB(0, 0);

    for (int s = 0; s < 32; ++s) {
        const int buf = s & 1;
        __syncthreads();
        if (s < 31) {
            stageA(s + 1, buf ^ 1);
            stageB(s + 1, buf ^ 1);
        }
        bf16x8_t af[4], bfr[4];
#pragma unroll
        for (int i = 0; i < 4; ++i) {
            af[i] = *(const bf16x8_t*)(&As[buf][0] + (size_t)(w * 64 + i * 16 + m16) * 80 + quad * 16);
            int nn = i * 16 + m16;
            bfr[i] = *(const bf16x8_t*)(&Bs[buf][0] + (nn * 4 + (quad ^ (nn & 3))) * 16);
        }
#pragma unroll
        for (int mi = 0; mi < 4; ++mi)
#pragma unroll
            for (int ni = 0; ni < 4; ++ni)
                acc[mi][ni] = __builtin_amdgcn_mfma_f32_16x16x32_bf16(
                    af[mi], bfr[ni], acc[mi][ni], 0, 0, 0);
    }

    float* Pb = P + (((size_t)(tap * 4 + b)) << 18) + p0;
#pragma unroll
    for (int mi = 0; mi < 4; ++mi)
#pragma unroll
        for (int e = 0; e < 4; ++e) {
            int oc = w * 64 + mi * 16 + quad * 4 + e;
            float* row = Pb + (size_t)oc * 1024 + m16;
#pragma unroll
            for (int ni = 0; ni < 4; ++ni)
                row[ni * 16] = acc[mi][ni][e];
        }
}

// ---------------------------------------------------------------------------
// Kernel 6c: x1 = relu(sum of 9 partials + b1), stored bf16
// ---------------------------------------------------------------------------
__global__ __launch_bounds__(256) void k_c1comb(const float* __restrict__ P,
                                                const float* __restrict__ b1,
                                                unsigned short* __restrict__ x1) {
    int id = blockIdx.x * 256 + threadIdx.x;  // 4-elem index, 0..262143
    int oc = (id >> 8) & 255;
    const float4* P4 = (const float4*)P;
    float bb = b1[oc];
    float4 a = P4[id];
    a.x += bb; a.y += bb; a.z += bb; a.w += bb;
#pragma unroll
    for (int tp = 1; tp < 9; ++tp) {
        float4 v = P4[id + tp * 262144];
        a.x += v.x; a.y += v.y; a.z += v.z; a.w += v.w;
    }
    float o0 = fmaxf(a.x, 0.f);
    float o1 = fmaxf(a.y, 0.f);
    float o2 = fmaxf(a.z, 0.f);
    float o3 = fmaxf(a.w, 0.f);
    uint2 r;
    r.x = (unsigned)f2bf(o0) | ((unsigned)f2bf(o1) << 16);
    r.y = (unsigned)f2bf(o2) | ((unsigned)f2bf(o3) << 16);
    ((uint2*)x1)[id] = r;
}

// ---------------------------------------------------------------------------
// Kernel 7a: pack w2 fp32 [256 oc][256 ic][9 tap] -> bf16 [tap][s(8)][oc][40]
// ---------------------------------------------------------------------------
__global__ __launch_bounds__(256) void k_w2pack(const float* __restrict__ w2,
                                                unsigned short* __restrict__ w2p) {
    int pid = blockIdx.x * 256 + threadIdx.x;  // 0..65535 = (oc,ic)
    int oc = pid >> 8, ic = pid & 255;
    const float* src = w2 + (size_t)pid * 9;
    float f[9];
#pragma unroll
    for (int tp = 0; tp < 9; ++tp) f[tp] = src[tp];
    int s = ic >> 5, j = ic & 31;
#pragma unroll
    for (int tp = 0; tp < 9; ++tp) {
        size_t row = ((size_t)(tp * 8 + s) * 256 + oc) * 40;
        w2p[row + j] = f2bf(f[tp]);
        if (j < 8) w2p[row + 32 + j] = 0;
    }
}

// ---------------------------------------------------------------------------
// Kernel 7b (MFMA): conv2 partials, one tap per block-z (x1 bf16 input).
// grid (16, 4, 9). 8 K-steps of BK=32. Valid conv: cols/rows >=30 garbage,
// pool never reads them.
// ---------------------------------------------------------------------------
__global__ __launch_bounds__(256) void k_conv2m(const unsigned short* __restrict__ x1,
                                                const unsigned short* __restrict__ w2p,
                                                float* __restrict__ P2) {
    __shared__ __align__(16) char As[2][20480];   // [buf][256 oc][40 bf16]
    __shared__ __align__(16) char Bs[2][4096];    // [buf][64 n][32 k] bf16 swz
    const int p0 = blockIdx.x * 64;
    const int b = blockIdx.y;
    const int tap = blockIdx.z;                   // kh*3+kw
    const int t = threadIdx.x;
    const int w = t >> 6, lane = t & 63;
    const int quad = lane >> 4, m16 = lane & 15;
    const int bn = t & 63, kg = t >> 6;
    const int e0 = p0 + bn;
    const int cidx = min(e0 + (tap / 3) * 32 + (tap % 3), 1023);
    const int bchunk = (bn * 4 + (kg ^ (bn & 3))) * 16;

    f32x4_t acc[4][4];
#pragma unroll
    for (int i = 0; i < 4; ++i)
#pragma unroll
        for (int j = 0; j < 4; ++j) acc[i][j] = (f32x4_t){0.f, 0.f, 0.f, 0.f};

    auto stageA = [&](int s, int buf) {
        const char* src = (const char*)(w2p + (size_t)(tap * 8 + s) * 10240);
#pragma unroll
        for (int i = 0; i < 5; ++i) {
            int idx = i * 4 + w;
            __builtin_amdgcn_global_load_lds(
                (const __attribute__((address_space(1))) void*)(src + idx * 1024 + lane * 16),
                (__attribute__((address_space(3))) void*)(&As[buf][0] + idx * 1024),
                16, 0, 0);
        }
    };
    auto stageB = [&](int s, int buf) {
        int ch = s * 32 + kg * 8;
        const unsigned short* plane = x1 + (((size_t)(b * 256 + ch)) << 10);
        unsigned short u[8];
#pragma unroll
        for (int j = 0; j < 8; ++j) u[j] = plane[((size_t)j << 10) + cidx];
        uint4 r4;
        r4.x = (unsigned)u[0] | ((unsigned)u[1] << 16);
        r4.y = (unsigned)u[2] | ((unsigned)u[3] << 16);
        r4.z = (unsigned)u[4] | ((unsigned)u[5] << 16);
        r4.w = (unsigned)u[6] | ((unsigned)u[7] << 16);
        *(uint4*)(&Bs[buf][bchunk]) = r4;
    };

    stageA(0, 0);
    stageB(0, 0);

    for (int s = 0; s < 8; ++s) {
        const int buf = s & 1;
        __syncthreads();
        if (s < 7) {
            stageA(s + 1, buf ^ 1);
            stageB(s + 1, buf ^ 1);
        }
        bf16x8_t af[4], bfr[4];
#pragma unroll
        for (int i = 0; i < 4; ++i) {
            af[i] = *(const bf16x8_t*)(&As[buf][0] + (size_t)(w * 64 + i * 16 + m16) * 80 + quad * 16);
            int nn = i * 16 + m16;
            bfr[i] = *(const bf16x8_t*)(&Bs[buf][0] + (nn * 4 + (quad ^ (nn & 3))) * 16);
        }
#pragma unroll
        for (int mi = 0; mi < 4; ++mi)
#pragma unroll
            for (int ni = 0; ni < 4; ++ni)
                acc[mi][ni] = __builtin_amdgcn_mfma_f32_16x16x32_bf16(
                    af[mi], bfr[ni], acc[mi][ni], 0, 0, 0);
    }

    float* Pb = P2 + (((size_t)(tap * 4 + b)) << 18) + p0;
#pragma unroll
    for (int mi = 0; mi < 4; ++mi)
#pragma unroll
        for (int e = 0; e < 4; ++e) {
            int oc = w * 64 + mi * 16 + quad * 4 + e;
            float* row = Pb + (size_t)oc * 1024 + m16;
#pragma unroll
            for (int ni = 0; ni < 4; ++ni)
                row[ni * 16] = acc[mi][ni][e];
        }
}

// ---------------------------------------------------------------------------
// Kernel 7c: combine 9 conv2 partials + bias, then 3x3/3 maxpool -> xp[4][256][100]
// ---------------------------------------------------------------------------
__global__ __launch_bounds__(256) void k_c2pool(const float* __restrict__ P2,
                                                const float* __restrict__ b2,
                                                float* __restrict__ xp) {
    int id = blockIdx.x * 256 + threadIdx.x;  // 0..102399
    int px = id % 10;
    int tmp = id / 10;
    int py = tmp % 10;
    int ch = tmp / 10;          // b*256 + oc
    int b = ch >> 8, oc = ch & 255;
    float bb = b2[oc];
    float m = -3.4e38f;
#pragma unroll
    for (int dy = 0; dy < 3; ++dy)
#pragma unroll
        for (int dx = 0; dx < 3; ++dx) {
            int pos = (3 * py + dy) * 32 + 3 * px + dx;
            float v = bb;
#pragma unroll
            for (int tp = 0; tp < 9; ++tp)
                v += P2[(((size_t)(tp * 4 + b)) << 18) + (size_t)oc * 1024 + pos];
            m = fmaxf(m, v);
        }
    xp[id] = m;
}

// ---------------------------------------------------------------------------
// Kernel 9: conv3 (256ch, 10x10 -> 8x8) + spatial mean + b3 -> weight[1,B]
// ---------------------------------------------------------------------------
__global__ __launch_bounds__(256) void k_conv3(const float* __restrict__ xp,
                                               const float* __restrict__ w3,
                                               const float* __restrict__ b3,
                                               float* __restrict__ out) {
    __shared__ float s[256];
    int b = blockIdx.x, t = threadIdx.x;
    int pos = t & 63, qi = t >> 6;
    int y = pos >> 3, x = pos & 7;
    float acc = 0.f;
    for (int ic = qi * 64; ic < qi * 64 + 64; ++ic) {
        const float* ip = xp + ((size_t)(b * 256 + ic)) * 100 + y * 10 + x;
#pragma unroll
        for (int kh = 0; kh < 3; ++kh)
#pragma unroll
            for (int kw = 0; kw < 3; ++kw)
                acc = fmaf(w3[ic * 9 + kh * 3 + kw], ip[kh * 10 + kw], acc);
    }
    s[t] = acc;
    __syncthreads();
    if (t < 64) {
        float v = s[t] + s[t + 64] + s[t + 128] + s[t + 192];
#pragma unroll
        for (int off = 32; off >= 1; off >>= 1) v += __shfl_down(v, off);
        if (t == 0) out[4194304 + b] = v * (1.f / 64.f) + b3[0];
    }
}

// ---------------------------------------------------------------------------
extern "C" void kernel_launch(void* const* d_in, const int* in_sizes, int n_in,
                              void* d_out, int out_size, void* d_ws, size_t ws_size,
                              hipStream_t stream) {
    (void)in_sizes; (void)n_in; (void)out_size; (void)ws_size;
    const float* fqf = (const float*)d_in[0];  // fq_feats [9,4,512,32,32]
    const float* fsf = (const float*)d_in[1];  // fs_feats
    const float* fqi = (const float*)d_in[2];  // f_q [4,512,32,32]
    const float* fsi = (const float*)d_in[3];  // f_s
    const float* w1  = (const float*)d_in[4];
    const float* b1  = (const float*)d_in[5];
    const float* w2  = (const float*)d_in[6];
    const float* b2  = (const float*)d_in[7];
    const float* w3  = (const float*)d_in[8];
    const float* b3  = (const float*)d_in[9];
    float* out = (float*)d_out;

    float* W = (float*)d_ws;
    // [0 .. 4,194,304) f32: P01 fp16 corr partials (8.4M ush); aliased by
    //   attfq fp32 (2.1M, post-softmax)
    unsigned short* P01u = (unsigned short*)W;
    float* attfq = W;
    // [4,194,304 .. 6,553,600): attn fp16 padded (4.7M ush); aliased by w1p
    //   (2.95M ush, dead after conv1m) and w2p (0.74M ush, post-attn)
    unsigned short* attn = (unsigned short*)(W + 4194304);
    unsigned short* w1p  = (unsigned short*)(W + 4194304);
    unsigned short* w2p  = (unsigned short*)(W + 4194304);
    // [6,553,600 .. 7,733,248): fs fp16 padded (2.36M ush)
    unsigned short* fsp = (unsigned short*)(W + 6553600);
    // [7,733,248 .. 8,257,536): x1 bf16 (1.05M ush)
    unsigned short* x1 = (unsigned short*)(W + 7733248);
    // [8,257,536 .. 8,359,936): xp fp32
    float* xp = W + 8257536;
    // [8,359,936 .. 17,797,120): fqb f16 tiles; aliased by conv partials P9
    //   (9x4x256x1024 f32 = 9,437,184 floats exactly) — P9 used only while
    //   fqb is dead (conv1 phase pre-k_prep; conv2 phase post-k_corr2)
    unsigned short* fqb = (unsigned short*)(W + 8359936);
    float* P9 = W + 8359936;
    // [17,797,120 .. 27,234,304): fsb f16 tiles
    unsigned short* fsb = (unsigned short*)(W + 17797120);

    // conv1 phase (w1p in attn region, P9 in fqb region — both dead later)
    hipLaunchKernelGGL(k_w1pack,  dim3(1024),      dim3(256), 0, stream, w1, w1p);
    hipLaunchKernelGGL(k_conv1m,  dim3(16, 4, 9),  dim3(256), 0, stream, fqi, fsi, w1p, P9);
    hipLaunchKernelGGL(k_c1comb,  dim3(1024),      dim3(256), 0, stream, P9, b1, x1);
    hipLaunchKernelGGL(k_fspack,  dim3(256),       dim3(256), 0, stream, fsi, fsp);
    // attention path
    hipLaunchKernelGGL(k_prep,    dim3(8, 36, 2),  dim3(256), 0, stream, fqf, fsf, fqb, fsb);
    hipLaunchKernelGGL(k_corr2,   dim3(512),       dim3(256), 0, stream, fqb, fsb, P01u);
    hipLaunchKernelGGL(k_softmax, dim3(4096),      dim3(256), 0, stream, P01u, attn);
    hipLaunchKernelGGL(k_attfqm,  dim3(8, 8, 4),   dim3(256), 0, stream, fsp, attn, attfq);
    hipLaunchKernelGGL(k_out,     dim3(16, 4),     dim3(256), 0, stream, fqi, attfq, out);
    // conv tail (w2p in attn region, P9 in fqb region — dead after k_out/corr2)
    hipLaunchKernelGGL(k_w2pack,  dim3(256),       dim3(256), 0, stream, w2, w2p);
    hipLaunchKernelGGL(k_conv2m,  dim3(16, 4, 9),  dim3(256), 0, stream, x1, w2p, P9);
    hipLaunchKernelGGL(k_c2pool,  dim3(400),       dim3(256), 0, stream, P9, b2, xp);
    hipLaunchKernelGGL(k_conv3,   dim3(4),         dim3(256), 0, stream, xp, w3, b3, out);
}

// Round 3
// 450.948 us; speedup vs baseline: 1.2846x; 1.1111x over previous
//
#include <hip/hip_runtime.h>
#include <hip/hip_bf16.h>

#define DI __device__ __forceinline__

typedef short bf16x8_t __attribute__((ext_vector_type(8)));
typedef _Float16 f16x8_t __attribute__((ext_vector_type(8)));
typedef float f32x4_t __attribute__((ext_vector_type(4)));

DI unsigned short f2bf(float f) {
    unsigned u = __float_as_uint(f);
    u += 0x7fffu + ((u >> 16) & 1u);
    return (unsigned short)(u >> 16);
}
DI float bfu2f(unsigned short u) { return __uint_as_float(((unsigned)u) << 16); }
DI unsigned short f2h(float f) {
    _Float16 h = (_Float16)f;
    unsigned short u;
    __builtin_memcpy(&u, &h, 2);
    return u;
}
DI float h2f(unsigned short u) {
    _Float16 h;
    __builtin_memcpy(&h, &u, 2);
    return (float)h;
}

// ---------------------------------------------------------------------------
// Kernel 1b: single-pass transpose/convert + fused norm computation.
// Reads [32ch][128pos] fp32 slices once; writes RAW f16 tiles (chunk-XOR
// swizzle for conflict-free ds_read_b128 in corr2) and accumulates per-pos
// sum-of-squares on the fly -> rq/rs (inverse norms). Normalization is
// applied in k_corr2's epilogue (relu(x*rq*rs) == relu(x)*rq*rs).
// grid (8 ptile, 36 lb, 2 tensor) x 256.
// ---------------------------------------------------------------------------
__global__ __launch_bounds__(256) void k_prep(const float* __restrict__ fqf,
                                              const float* __restrict__ fsf,
                                              unsigned short* __restrict__ fqb,
                                              unsigned short* __restrict__ fsb,
                                              float* __restrict__ rq,
                                              float* __restrict__ rs) {
    __shared__ float T[128 * 33];   // transposed fp32 sub-tile [pos][33]
    const int pt = blockIdx.x;
    const int lb = blockIdx.y;
    const int tz = blockIdx.z;
    const float* src = (tz ? fsf : fqf) + (size_t)lb * 524288 + pt * 128;
    unsigned short* dst = (tz ? fsb : fqb) + (((size_t)(lb * 8 + pt)) << 16);
    float* rdst = (tz ? rs : rq) + lb * 1024 + pt * 128;
    const int t = threadIdx.x;

    // phase-C per-thread constants (2 chunks: c = t and t+256)
    const int m0 = t >> 2, m1 = 64 + (t >> 2);
    const int q0 = (t & 3) ^ ((m0 >> 2) & 3);
    const int q1 = (t & 3) ^ ((m1 >> 2) & 3);
    float ssq0 = 0.f, ssq1 = 0.f;

    // phase-B per-thread constants
    const int brow = t >> 5;             // channel 0..7 (+j*8 below? no: row idx)
    // mapping: f = t + j*256 -> row = f>>5 (0..31), m4 = (f&31)*4
    float4 v[4];
    auto load = [&](int ks) {
#pragma unroll
        for (int j = 0; j < 4; ++j) {
            int f = t + (j << 8);
            int row = f >> 5;
            int m4 = (f & 31) << 2;
            v[j] = *(const float4*)(src + (((size_t)(ks * 32 + row)) << 10) + m4);
        }
    };

    load(0);
    for (int ks = 0; ks < 16; ++ks) {
        __syncthreads();                 // T free (prev phase-C reads done)
#pragma unroll
        for (int j = 0; j < 4; ++j) {
            int f = t + (j << 8);
            int row = f >> 5;
            int m4 = (f & 31) << 2;
            T[(m4 + 0) * 33 + row] = v[j].x;
            T[(m4 + 1) * 33 + row] = v[j].y;
            T[(m4 + 2) * 33 + row] = v[j].z;
            T[(m4 + 3) * 33 + row] = v[j].w;
        }
        __syncthreads();                 // T ready
        if (ks < 15) load(ks + 1);       // prefetch overlaps phase C
        // phase C: read T, convert raw f16, swizzled chunk writes, accum ssq
        {
            const float* Tp = &T[m0 * 33 + q0 * 8];
            float f0 = Tp[0], f1 = Tp[1], f2 = Tp[2], f3 = Tp[3];
            float f4 = Tp[4], f5 = Tp[5], f6 = Tp[6], f7 = Tp[7];
            ssq0 += f0 * f0 + f1 * f1 + f2 * f2 + f3 * f3 +
                    f4 * f4 + f5 * f5 + f6 * f6 + f7 * f7;
            uint4 r4;
            r4.x = (unsigned)f2h(f0) | ((unsigned)f2h(f1) << 16);
            r4.y = (unsigned)f2h(f2) | ((unsigned)f2h(f3) << 16);
            r4.z = (unsigned)f2h(f4) | ((unsigned)f2h(f5) << 16);
            r4.w = (unsigned)f2h(f6) | ((unsigned)f2h(f7) << 16);
            *(uint4*)(dst + ((size_t)ks << 12) + ((size_t)t << 3)) = r4;
        }
        {
            const float* Tp = &T[m1 * 33 + q1 * 8];
            float f0 = Tp[0], f1 = Tp[1], f2 = Tp[2], f3 = Tp[3];
            float f4 = Tp[4], f5 = Tp[5], f6 = Tp[6], f7 = Tp[7];
            ssq1 += f0 * f0 + f1 * f1 + f2 * f2 + f3 * f3 +
                    f4 * f4 + f5 * f5 + f6 * f6 + f7 * f7;
            uint4 r4;
            r4.x = (unsigned)f2h(f0) | ((unsigned)f2h(f1) << 16);
            r4.y = (unsigned)f2h(f2) | ((unsigned)f2h(f3) << 16);
            r4.z = (unsigned)f2h(f4) | ((unsigned)f2h(f5) << 16);
            r4.w = (unsigned)f2h(f6) | ((unsigned)f2h(f7) << 16);
            *(uint4*)(dst + ((size_t)ks << 12) + ((size_t)(t + 256) << 3)) = r4;
        }
    }
    // reduce ssq across the 4 lanes sharing each position (4-aligned groups)
    ssq0 += __shfl_xor(ssq0, 1); ssq0 += __shfl_xor(ssq0, 2);
    ssq1 += __shfl_xor(ssq1, 1); ssq1 += __shfl_xor(ssq1, 2);
    if ((t & 3) == 0) {
        rdst[m0] = 1.f / fmaxf(sqrtf(ssq0), 1e-12f);
        rdst[m1] = 1.f / fmaxf(sqrtf(ssq1), 1e-12f);
    }
}

// ---------------------------------------------------------------------------
// Kernel 2b (raw f16 tiles): corr partials, 2-way level split. Normalization
// (rq*rs) applied in the per-level ReLU epilogue.
// grid dim3(512): id&7 -> (b,lg) so each XCD owns one (b,lg) (L2 locality);
// id>>3 -> 8x8 (q,s) tile. Staging = linear global_load_lds of 8 KB tile
// images; fragments = single ds_read_b128 (chunk-XOR swizzle).
// ---------------------------------------------------------------------------
__global__ __launch_bounds__(256) void k_corr2(const unsigned short* __restrict__ fqb,
                                               const unsigned short* __restrict__ fsb,
                                               const float* __restrict__ rq,
                                               const float* __restrict__ rs,
                                               unsigned short* __restrict__ P01) {
    __shared__ __align__(16) char L[2][16384];   // A 8 KB | B 8 KB per buf
    const int id = blockIdx.x;
    const int z = id & 7, local = id >> 3;       // z -> XCD-resident (b,lg)
    const int b = z >> 1, lg = z & 1;
    const int qt = local >> 3, st = local & 7;
    const int q0 = qt * 128, s0 = st * 128;
    const int t = threadIdx.x;
    const int w = t >> 6, lane = t & 63;
    const int wrow = w >> 1, wcol = w & 1;
    const int quad = lane >> 4, m16 = lane & 15;
    const int nsteps = (5 - lg) << 4;            // lg0: 80, lg1: 64

    f32x4_t zero4 = {0.f, 0.f, 0.f, 0.f};
    f32x4_t master[4][4], lvl[4][4];
#pragma unroll
    for (int i = 0; i < 4; ++i)
#pragma unroll
        for (int j = 0; j < 4; ++j) { master[i][j] = zero4; lvl[i][j] = zero4; }

    auto stage = [&](int step, int buf) {
        int g = step >> 4, ks = step & 15;
        int lb = (lg + 2 * g) * 4 + b;
        const unsigned short* Ab = fqb + ((((size_t)lb * 8 + qt) * 16 + ks) << 12);
        const unsigned short* Bb = fsb + ((((size_t)lb * 8 + st) * 16 + ks) << 12);
#pragma unroll
        for (int i = 0; i < 4; ++i) {
            int idx0 = i * 256 + w * 64;   // wave-uniform; A:0..511, B:512..1023
            int idx = idx0 + lane;
            const unsigned short* srcp = (idx0 < 512)
                ? (Ab + ((size_t)idx << 3))
                : (Bb + ((size_t)(idx - 512) << 3));
            __builtin_amdgcn_global_load_lds(
                (const __attribute__((address_space(1))) void*)srcp,
                (__attribute__((address_space(3))) void*)(&L[buf][0] + idx0 * 16),
                16, 0, 0);
        }
    };

    stage(0, 0);
    for (int step = 0; step < nsteps; ++step) {
        const int buf = step & 1;
        __syncthreads();
        if (step < nsteps - 1) stage(step + 1, buf ^ 1);
        const char* base = &L[buf][0];
        f16x8_t af[4], bfr[4];
#pragma unroll
        for (int i = 0; i < 4; ++i) {
            int m = wrow * 64 + i * 16 + m16;
            int sa = quad ^ ((m >> 2) & 3);
            af[i] = *(const f16x8_t*)(base + m * 64 + sa * 16);
            int n = wcol * 64 + i * 16 + m16;
            int sb = quad ^ ((n >> 2) & 3);
            bfr[i] = *(const f16x8_t*)(base + 8192 + n * 64 + sb * 16);
        }
#pragma unroll
        for (int mi = 0; mi < 4; ++mi)
#pragma unroll
            for (int ni = 0; ni < 4; ++ni)
                lvl[mi][ni] = __builtin_amdgcn_mfma_f32_16x16x32_f16(
                    af[mi], bfr[ni], lvl[mi][ni], 0, 0, 0);

        if ((step & 15) == 15) {   // end of a level: normalize + ReLU + accum
            int lb = (lg + 2 * (step >> 4)) * 4 + b;
            const float* rqb = rq + lb * 1024 + q0 + wrow * 64;
            const float* rsb = rs + lb * 1024 + s0 + wcol * 64;
            float rq4[4][4], rsv[4];
#pragma unroll
            for (int mi = 0; mi < 4; ++mi) {
                float4 vv = *(const float4*)(rqb + mi * 16 + quad * 4);
                rq4[mi][0] = vv.x; rq4[mi][1] = vv.y; rq4[mi][2] = vv.z; rq4[mi][3] = vv.w;
            }
#pragma unroll
            for (int ni = 0; ni < 4; ++ni) rsv[ni] = rsb[ni * 16 + m16];
#pragma unroll
            for (int mi = 0; mi < 4; ++mi)
#pragma unroll
                for (int ni = 0; ni < 4; ++ni) {
#pragma unroll
                    for (int e = 0; e < 4; ++e)
                        master[mi][ni][e] += fmaxf(lvl[mi][ni][e] * rq4[mi][e] * rsv[ni], 0.f);
                    lvl[mi][ni] = zero4;
                }
        }
    }

#pragma unroll
    for (int mi = 0; mi < 4; ++mi)
#pragma unroll
        for (int e = 0; e < 4; ++e) {
            int q = q0 + wrow * 64 + mi * 16 + quad * 4 + e;
            unsigned short* cp = P01 + ((((size_t)(lg * 4 + b)) * 1024 + q) << 10)
                                 + s0 + wcol * 64 + m16;
#pragma unroll
            for (int ni = 0; ni < 4; ++ni)
                cp[ni * 16] = f2h(master[mi][ni][e]);
        }
}

// ---------------------------------------------------------------------------
// Kernel 3: softmax over s. Reads 2 fp16 partials, scale 20/9, writes attn as
// padded fp16 [b][sb(32)][q][36] for MFMA staging.
// ---------------------------------------------------------------------------
__global__ __launch_bounds__(256) void k_softmax(const unsigned short* __restrict__ P01,
                                                 unsigned short* __restrict__ attn) {
    __shared__ float red[8];
    const int row = blockIdx.x;  // 0..4095
    const int b = row >> 10, q = row & 1023;
    const int t = threadIdx.x;
    const unsigned short* p0 = P01 + (((size_t)b << 20) + ((size_t)q << 10)) + t * 4;
    const unsigned short* p1 = p0 + ((size_t)4 << 20);
    uint2 a0 = *(const uint2*)p0;
    uint2 a1 = *(const uint2*)p1;
    const float SC = 20.f / 9.f;
    float v0 = (h2f(a0.x & 0xffff) + h2f(a1.x & 0xffff)) * SC;
    float v1 = (h2f(a0.x >> 16)    + h2f(a1.x >> 16)) * SC;
    float v2 = (h2f(a0.y & 0xffff) + h2f(a1.y & 0xffff)) * SC;
    float v3 = (h2f(a0.y >> 16)    + h2f(a1.y >> 16)) * SC;
    float m = fmaxf(fmaxf(v0, v1), fmaxf(v2, v3));
#pragma unroll
    for (int off = 32; off >= 1; off >>= 1) m = fmaxf(m, __shfl_down(m, off));
    const int wid = t >> 6, lane = t & 63;
    if (lane == 0) red[wid] = m;
    __syncthreads();
    m = fmaxf(fmaxf(red[0], red[1]), fmaxf(red[2], red[3]));
    float e0 = __expf(v0 - m), e1 = __expf(v1 - m);
    float e2 = __expf(v2 - m), e3 = __expf(v3 - m);
    float s = e0 + e1 + e2 + e3;
#pragma unroll
    for (int off = 32; off >= 1; off >>= 1) s += __shfl_down(s, off);
    if (lane == 0) red[4 + wid] = s;
    __syncthreads();
    s = red[4] + red[5] + red[6] + red[7];
    float inv = 1.f / s;
    unsigned short* o = attn + (size_t)((b * 32 + (t >> 3)) * 1024 + q) * 36 + (t & 7) * 4;
    uint2 r;
    r.x = (unsigned)f2h(e0 * inv) | ((unsigned)f2h(e1 * inv) << 16);
    r.y = (unsigned)f2h(e2 * inv) | ((unsigned)f2h(e3 * inv) << 16);
    *(uint2*)o = r;
}

// ---------------------------------------------------------------------------
// Kernel 4a: pack f_s fp32 [b][c][s] -> fp16 [b][sb(32)][c][36]
// ---------------------------------------------------------------------------
__global__ __launch_bounds__(256) void k_fspack(const float* __restrict__ fsi,
                                                unsigned short* __restrict__ fsp) {
    int id = blockIdx.x * 256 + threadIdx.x;  // 0..65535
    int c = id & 511, sb = (id >> 9) & 31, b = id >> 14;
    const float4* src = (const float4*)(fsi + (((size_t)(b * 512 + c)) << 10) + sb * 32);
    unsigned short* dst = fsp + (size_t)((b * 32 + sb) * 512 + c) * 36;
#pragma unroll
    for (int j = 0; j < 8; ++j) {
        float4 v = src[j];
        uint2 r;
        r.x = (unsigned)f2h(v.x) | ((unsigned)f2h(v.y) << 16);
        r.y = (unsigned)f2h(v.z) | ((unsigned)f2h(v.w) << 16);
        *(uint2*)(dst + j * 4) = r;
    }
}

// ---------------------------------------------------------------------------
// Kernel 4b (MFMA f16): att_fq[b,c,q] = sum_s attn[q,s] * f_s[c,s]
// ---------------------------------------------------------------------------
__global__ __launch_bounds__(256) void k_attfqm(const unsigned short* __restrict__ fsp,
                                                const unsigned short* __restrict__ attn,
                                                float* __restrict__ attfq) {
    __shared__ __align__(16) char L[2][14336];  // A 4608 B | B 9216 B | pad 512
    const int q0 = blockIdx.x * 128;
    const int c0 = blockIdx.y * 64;
    const int b  = blockIdx.z;
    const int t = threadIdx.x;
    const int w = t >> 6, lane = t & 63;
    const int quad = lane >> 4, m16 = lane & 15;

    f32x4_t acc[4][2];
#pragma unroll
    for (int i = 0; i < 4; ++i)
#pragma unroll
        for (int j = 0; j < 2; ++j) acc[i][j] = (f32x4_t){0.f, 0.f, 0.f, 0.f};

    auto stage = [&](int sb, int buf) {
        const char* sa = (const char*)(fsp + (size_t)((b * 32 + sb) * 512 + c0) * 36);
        const char* sbp = (const char*)(attn + (size_t)((b * 32 + sb) * 1024 + q0) * 36);
#pragma unroll
        for (int i = 0; i < 4; ++i) {
            int idx0 = i * 256 + w * 64;          // wave-uniform chunk base
            if (idx0 < 896) {                      // uniform predicate (pad reads ok)
                int idx = idx0 + lane;
                const char* src = (idx < 288) ? (sa + idx * 16) : (sbp + (idx - 288) * 16);
                __builtin_amdgcn_global_load_lds(
                    (const __attribute__((address_space(1))) void*)src,
                    (__attribute__((address_space(3))) void*)(&L[buf][0] + idx0 * 16),
                    16, 0, 0);
            }
        }
    };

    stage(0, 0);
    for (int sb = 0; sb < 32; ++sb) {
        const int buf = sb & 1;
        __syncthreads();
        if (sb < 31) stage(sb + 1, buf ^ 1);
        const char* base = &L[buf][0];
        f16x8_t af[4], bfr[2];
#pragma unroll
        for (int i = 0; i < 4; ++i) {
            const char* ap = base + (size_t)(i * 16 + m16) * 72 + quad * 16;
            union { unsigned long long d[2]; f16x8_t v; } u;
            u.d[0] = *(const unsigned long long*)ap;
            u.d[1] = *(const unsigned long long*)(ap + 8);
            af[i] = u.v;
        }
#pragma unroll
        for (int ni = 0; ni < 2; ++ni) {
            const char* bp = base + 4608 + (size_t)(w * 32 + ni * 16 + m16) * 72 + quad * 16;
            union { unsigned long long d[2]; f16x8_t v; } u;
            u.d[0] = *(const unsigned long long*)bp;
            u.d[1] = *(const unsigned long long*)(bp + 8);
            bfr[ni] = u.v;
        }
#pragma unroll
        for (int mi = 0; mi < 4; ++mi)
#pragma unroll
            for (int ni = 0; ni < 2; ++ni)
                acc[mi][ni] = __builtin_amdgcn_mfma_f32_16x16x32_f16(
                    af[mi], bfr[ni], acc[mi][ni], 0, 0, 0);
    }

#pragma unroll
    for (int mi = 0; mi < 4; ++mi)
#pragma unroll
        for (int e = 0; e < 4; ++e) {
            int c = c0 + mi * 16 + quad * 4 + e;
            float* rowp = attfq + (((size_t)(b * 512 + c)) << 10) + q0 + w * 32 + m16;
#pragma unroll
            for (int ni = 0; ni < 2; ++ni)
                rowp[ni * 16] = acc[mi][ni][e];
        }
}

// ---------------------------------------------------------------------------
// Kernel 5: fq = l2n(f_q,C) + 0.5*l2n(att_fq,C); write fq & att_fq (fp32).
// ---------------------------------------------------------------------------
__global__ __launch_bounds__(256) void k_out(const float* __restrict__ fqi,
                                             const float* __restrict__ attfq,
                                             float* __restrict__ out) {
    __shared__ float redq[256], reda[256];
    __shared__ float rnq[64], rna[64];
    const int b = blockIdx.y;
    const int p0 = blockIdx.x * 64;
    const int t = threadIdx.x;
    const int pl = t & 63, cg = t >> 6;
    const int pos = p0 + pl;
    const float* qp = fqi + (((size_t)b) << 19) + pos;
    const float* ap = attfq + (((size_t)b) << 19) + pos;
    float sq = 0.f, sa = 0.f;
    for (int c = cg * 128; c < cg * 128 + 128; ++c) {
        float q = qp[(size_t)c << 10];
        float a = ap[(size_t)c << 10];
        sq += q * q;
        sa += a * a;
    }
    redq[t] = sq; reda[t] = sa;
    __syncthreads();
    if (t < 64) {
        float q = redq[t] + redq[t + 64] + redq[t + 128] + redq[t + 192];
        float a = reda[t] + reda[t + 64] + reda[t + 128] + reda[t + 192];
        rnq[t] = 1.f / fmaxf(sqrtf(q), 1e-12f);
        rna[t] = 1.f / fmaxf(sqrtf(a), 1e-12f);
    }
    __syncthreads();
    const float RQ = rnq[pl], RA = 0.5f * rna[pl];
    float* o1 = out + (((size_t)b) << 19) + pos;
    float* o2 = o1 + 2097152;
    for (int c = cg * 128; c < cg * 128 + 128; ++c) {
        float q = qp[(size_t)c << 10];
        float a = ap[(size_t)c << 10];
        o1[(size_t)c << 10] = q * RQ + a * RA;
        o2[(size_t)c << 10] = a;
    }
}

// ---------------------------------------------------------------------------
// Kernel 6a: pack w1 fp32 [256 oc][1024 ic][9 tap] -> bf16 [tap][s(32)][oc][40]
// ---------------------------------------------------------------------------
__global__ __launch_bounds__(256) void k_w1pack(const float* __restrict__ w1,
                                                unsigned short* __restrict__ w1p) {
    int pid = blockIdx.x * 256 + threadIdx.x;  // 0..262143 = (oc,ic)
    int oc = pid >> 10, ic = pid & 1023;
    const float* src = w1 + (size_t)pid * 9;
    float f[9];
#pragma unroll
    for (int tp = 0; tp < 9; ++tp) f[tp] = src[tp];
    int s = ic >> 5, j = ic & 31;
#pragma unroll
    for (int tp = 0; tp < 9; ++tp) {
        size_t row = ((size_t)(tp * 32 + s) * 256 + oc) * 40;
        w1p[row + j] = f2bf(f[tp]);
        if (j < 8) w1p[row + 32 + j] = 0;
    }
}

// ---------------------------------------------------------------------------
// Kernel 6b (MFMA): conv1 partials, one tap per block-z (9-way K split).
// grid (16 pos-tiles, 4 b, 9 tap). 32 K-steps of BK=32 channels.
// ---------------------------------------------------------------------------
__global__ __launch_bounds__(256) void k_conv1m(const float* __restrict__ fqi,
                                                const float* __restrict__ fsi,
                                                const unsigned short* __restrict__ w1p,
                                                float* __restrict__ P) {
    __shared__ __align__(16) char As[2][20480];   // [buf][256 oc][40 bf16]
    __shared__ __align__(16) char Bs[2][4096];    // [buf][64 n][32 k] bf16 swz
    const int p0 = blockIdx.x * 64;
    const int b = blockIdx.y;
    const int tap = blockIdx.z;                   // kh*3+kw
    const int dy = 2 * (tap / 3) - 2;
    const int dx = 2 * (tap % 3) - 2;
    const int t = threadIdx.x;
    const int w = t >> 6, lane = t & 63;
    const int quad = lane >> 4, m16 = lane & 15;
    const int bn = t & 63, kg = t >> 6;
    const int e0 = p0 + bn;
    const bool valid = ((unsigned)((e0 >> 5) + dy) < 32u) &&
                       ((unsigned)((e0 & 31) + dx) < 32u);
    const int cidx = min(max(e0 + dy * 32 + dx, 0), 1023);
    const int bchunk = (bn * 4 + (kg ^ (bn & 3))) * 16;

    f32x4_t acc[4][4];
#pragma unroll
    for (int i = 0; i < 4; ++i)
#pragma unroll
        for (int j = 0; j < 4; ++j) acc[i][j] = (f32x4_t){0.f, 0.f, 0.f, 0.f};

    auto stageA = [&](int s, int buf) {
        const char* src = (const char*)(w1p + (size_t)(tap * 32 + s) * 10240);
#pragma unroll
        for (int i = 0; i < 5; ++i) {
            int idx = i * 4 + w;
            __builtin_amdgcn_global_load_lds(
                (const __attribute__((address_space(1))) void*)(src + idx * 1024 + lane * 16),
                (__attribute__((address_space(3))) void*)(&As[buf][0] + idx * 1024),
                16, 0, 0);
        }
    };
    auto stageB = [&](int s, int buf) {
        int ch = s * 32 + kg * 8;                 // 8-ch group never straddles 512
        const float* plane = (ch < 512)
            ? (fqi + (((size_t)(b * 512 + ch)) << 10))
            : (fsi + (((size_t)(b * 512 + ch - 512)) << 10));
        float f[8];
#pragma unroll
        for (int j = 0; j < 8; ++j) {
            float v = plane[((size_t)j << 10) + cidx];
            f[j] = valid ? v : 0.f;
        }
        uint4 r4;
        r4.x = (unsigned)f2bf(f[0]) | ((unsigned)f2bf(f[1]) << 16);
        r4.y = (unsigned)f2bf(f[2]) | ((unsigned)f2bf(f[3]) << 16);
        r4.z = (unsigned)f2bf(f[4]) | ((unsigned)f2bf(f[5]) << 16);
        r4.w = (unsigned)f2bf(f[6]) | ((unsigned)f2bf(f[7]) << 16);
        *(uint4*)(&Bs[buf][bchunk]) = r4;
    };

    stageA(0, 0);
    stageB(0, 0);

    for (int s = 0; s < 32; ++s) {
        const int buf = s & 1;
        __syncthreads();
        if (s < 31) {
            stageA(s + 1, buf ^ 1);
            stageB(s + 1, buf ^ 1);
        }
        bf16x8_t af[4], bfr[4];
#pragma unroll
        for (int i = 0; i < 4; ++i) {
            af[i] = *(const bf16x8_t*)(&As[buf][0] + (size_t)(w * 64 + i * 16 + m16) * 80 + quad * 16);
            int nn = i * 16 + m16;
            bfr[i] = *(const bf16x8_t*)(&Bs[buf][0] + (nn * 4 + (quad ^ (nn & 3))) * 16);
        }
#pragma unroll
        for (int mi = 0; mi < 4; ++mi)
#pragma unroll
            for (int ni = 0; ni < 4; ++ni)
                acc[mi][ni] = __builtin_amdgcn_mfma_f32_16x16x32_bf16(
                    af[mi], bfr[ni], acc[mi][ni], 0, 0, 0);
    }

    float* Pb = P + (((size_t)(tap * 4 + b)) << 18) + p0;
#pragma unroll
    for (int mi = 0; mi < 4; ++mi)
#pragma unroll
        for (int e = 0; e < 4; ++e) {
            int oc = w * 64 + mi * 16 + quad * 4 + e;
            float* row = Pb + (size_t)oc * 1024 + m16;
#pragma unroll
            for (int ni = 0; ni < 4; ++ni)
                row[ni * 16] = acc[mi][ni][e];
        }
}

// ---------------------------------------------------------------------------
// Kernel 6c: x1 = relu(sum of 9 partials + b1), stored bf16
// ---------------------------------------------------------------------------
__global__ __launch_bounds__(256) void k_c1comb(const float* __restrict__ P,
                                                const float* __restrict__ b1,
                                                unsigned short* __restrict__ x1) {
    int id = blockIdx.x * 256 + threadIdx.x;  // 4-elem index, 0..262143
    int oc = (id >> 8) & 255;
    const float4* P4 = (const float4*)P;
    float bb = b1[oc];
    float4 a = P4[id];
    a.x += bb; a.y += bb; a.z += bb; a.w += bb;
#pragma unroll
    for (int tp = 1; tp < 9; ++tp) {
        float4 v = P4[id + tp * 262144];
        a.x += v.x; a.y += v.y; a.z += v.z; a.w += v.w;
    }
    float o0 = fmaxf(a.x, 0.f);
    float o1 = fmaxf(a.y, 0.f);
    float o2 = fmaxf(a.z, 0.f);
    float o3 = fmaxf(a.w, 0.f);
    uint2 r;
    r.x = (unsigned)f2bf(o0) | ((unsigned)f2bf(o1) << 16);
    r.y = (unsigned)f2bf(o2) | ((unsigned)f2bf(o3) << 16);
    ((uint2*)x1)[id] = r;
}

// ---------------------------------------------------------------------------
// Kernel 7a: pack w2 fp32 [256 oc][256 ic][9 tap] -> bf16 [tap][s(8)][oc][40]
// ---------------------------------------------------------------------------
__global__ __launch_bounds__(256) void k_w2pack(const float* __restrict__ w2,
                                                unsigned short* __restrict__ w2p) {
    int pid = blockIdx.x * 256 + threadIdx.x;  // 0..65535 = (oc,ic)
    int oc = pid >> 8, ic = pid & 255;
    const float* src = w2 + (size_t)pid * 9;
    float f[9];
#pragma unroll
    for (int tp = 0; tp < 9; ++tp) f[tp] = src[tp];
    int s = ic >> 5, j = ic & 31;
#pragma unroll
    for (int tp = 0; tp < 9; ++tp) {
        size_t row = ((size_t)(tp * 8 + s) * 256 + oc) * 40;
        w2p[row + j] = f2bf(f[tp]);
        if (j < 8) w2p[row + 32 + j] = 0;
    }
}

// ---------------------------------------------------------------------------
// Kernel 7b (MFMA): conv2 partials, one tap per block-z (x1 bf16 input).
// grid (16, 4, 9). 8 K-steps of BK=32.
// ---------------------------------------------------------------------------
__global__ __launch_bounds__(256) void k_conv2m(const unsigned short* __restrict__ x1,
                                                const unsigned short* __restrict__ w2p,
                                                float* __restrict__ P2) {
    __shared__ __align__(16) char As[2][20480];   // [buf][256 oc][40 bf16]
    __shared__ __align__(16) char Bs[2][4096];    // [buf][64 n][32 k] bf16 swz
    const int p0 = blockIdx.x * 64;
    const int b = blockIdx.y;
    const int tap = blockIdx.z;                   // kh*3+kw
    const int t = threadIdx.x;
    const int w = t >> 6, lane = t & 63;
    const int quad = lane >> 4, m16 = lane & 15;
    const int bn = t & 63, kg = t >> 6;
    const int e0 = p0 + bn;
    const int cidx = min(e0 + (tap / 3) * 32 + (tap % 3), 1023);
    const int bchunk = (bn * 4 + (kg ^ (bn & 3))) * 16;

    f32x4_t acc[4][4];
#pragma unroll
    for (int i = 0; i < 4; ++i)
#pragma unroll
        for (int j = 0; j < 4; ++j) acc[i][j] = (f32x4_t){0.f, 0.f, 0.f, 0.f};

    auto stageA = [&](int s, int buf) {
        const char* src = (const char*)(w2p + (size_t)(tap * 8 + s) * 10240);
#pragma unroll
        for (int i = 0; i < 5; ++i) {
            int idx = i * 4 + w;
            __builtin_amdgcn_global_load_lds(
                (const __attribute__((address_space(1))) void*)(src + idx * 1024 + lane * 16),
                (__attribute__((address_space(3))) void*)(&As[buf][0] + idx * 1024),
                16, 0, 0);
        }
    };
    auto stageB = [&](int s, int buf) {
        int ch = s * 32 + kg * 8;
        const unsigned short* plane = x1 + (((size_t)(b * 256 + ch)) << 10);
        unsigned short u[8];
#pragma unroll
        for (int j = 0; j < 8; ++j) u[j] = plane[((size_t)j << 10) + cidx];
        uint4 r4;
        r4.x = (unsigned)u[0] | ((unsigned)u[1] << 16);
        r4.y = (unsigned)u[2] | ((unsigned)u[3] << 16);
        r4.z = (unsigned)u[4] | ((unsigned)u[5] << 16);
        r4.w = (unsigned)u[6] | ((unsigned)u[7] << 16);
        *(uint4*)(&Bs[buf][bchunk]) = r4;
    };

    stageA(0, 0);
    stageB(0, 0);

    for (int s = 0; s < 8; ++s) {
        const int buf = s & 1;
        __syncthreads();
        if (s < 7) {
            stageA(s + 1, buf ^ 1);
            stageB(s + 1, buf ^ 1);
        }
        bf16x8_t af[4], bfr[4];
#pragma unroll
        for (int i = 0; i < 4; ++i) {
            af[i] = *(const bf16x8_t*)(&As[buf][0] + (size_t)(w * 64 + i * 16 + m16) * 80 + quad * 16);
            int nn = i * 16 + m16;
            bfr[i] = *(const bf16x8_t*)(&Bs[buf][0] + (nn * 4 + (quad ^ (nn & 3))) * 16);
        }
#pragma unroll
        for (int mi = 0; mi < 4; ++mi)
#pragma unroll
            for (int ni = 0; ni < 4; ++ni)
                acc[mi][ni] = __builtin_amdgcn_mfma_f32_16x16x32_bf16(
                    af[mi], bfr[ni], acc[mi][ni], 0, 0, 0);
    }

    float* Pb = P2 + (((size_t)(tap * 4 + b)) << 18) + p0;
#pragma unroll
    for (int mi = 0; mi < 4; ++mi)
#pragma unroll
        for (int e = 0; e < 4; ++e) {
            int oc = w * 64 + mi * 16 + quad * 4 + e;
            float* row = Pb + (size_t)oc * 1024 + m16;
#pragma unroll
            for (int ni = 0; ni < 4; ++ni)
                row[ni * 16] = acc[mi][ni][e];
        }
}

// ---------------------------------------------------------------------------
// Kernel 7c: combine 9 conv2 partials + bias, then 3x3/3 maxpool -> xp[4][256][100]
// ---------------------------------------------------------------------------
__global__ __launch_bounds__(256) void k_c2pool(const float* __restrict__ P2,
                                                const float* __restrict__ b2,
                                                float* __restrict__ xp) {
    int id = blockIdx.x * 256 + threadIdx.x;  // 0..102399
    int px = id % 10;
    int tmp = id / 10;
    int py = tmp % 10;
    int ch = tmp / 10;          // b*256 + oc
    int b = ch >> 8, oc = ch & 255;
    float bb = b2[oc];
    float m = -3.4e38f;
#pragma unroll
    for (int dy = 0; dy < 3; ++dy)
#pragma unroll
        for (int dx = 0; dx < 3; ++dx) {
            int pos = (3 * py + dy) * 32 + 3 * px + dx;
            float v = bb;
#pragma unroll
            for (int tp = 0; tp < 9; ++tp)
                v += P2[(((size_t)(tp * 4 + b)) << 18) + (size_t)oc * 1024 + pos];
            m = fmaxf(m, v);
        }
    xp[id] = m;
}

// ---------------------------------------------------------------------------
// Kernel 9: conv3 (256ch, 10x10 -> 8x8) + spatial mean + b3 -> weight[1,B]
// ---------------------------------------------------------------------------
__global__ __launch_bounds__(256) void k_conv3(const float* __restrict__ xp,
                                               const float* __restrict__ w3,
                                               const float* __restrict__ b3,
                                               float* __restrict__ out) {
    __shared__ float s[256];
    int b = blockIdx.x, t = threadIdx.x;
    int pos = t & 63, qi = t >> 6;
    int y = pos >> 3, x = pos & 7;
    float acc = 0.f;
    for (int ic = qi * 64; ic < qi * 64 + 64; ++ic) {
        const float* ip = xp + ((size_t)(b * 256 + ic)) * 100 + y * 10 + x;
#pragma unroll
        for (int kh = 0; kh < 3; ++kh)
#pragma unroll
            for (int kw = 0; kw < 3; ++kw)
                acc = fmaf(w3[ic * 9 + kh * 3 + kw], ip[kh * 10 + kw], acc);
    }
    s[t] = acc;
    __syncthreads();
    if (t < 64) {
        float v = s[t] + s[t + 64] + s[t + 128] + s[t + 192];
#pragma unroll
        for (int off = 32; off >= 1; off >>= 1) v += __shfl_down(v, off);
        if (t == 0) out[4194304 + b] = v * (1.f / 64.f) + b3[0];
    }
}

// ---------------------------------------------------------------------------
extern "C" void kernel_launch(void* const* d_in, const int* in_sizes, int n_in,
                              void* d_out, int out_size, void* d_ws, size_t ws_size,
                              hipStream_t stream) {
    (void)in_sizes; (void)n_in; (void)out_size; (void)ws_size;
    const float* fqf = (const float*)d_in[0];  // fq_feats [9,4,512,32,32]
    const float* fsf = (const float*)d_in[1];  // fs_feats
    const float* fqi = (const float*)d_in[2];  // f_q [4,512,32,32]
    const float* fsi = (const float*)d_in[3];  // f_s
    const float* w1  = (const float*)d_in[4];
    const float* b1  = (const float*)d_in[5];
    const float* w2  = (const float*)d_in[6];
    const float* b2  = (const float*)d_in[7];
    const float* w3  = (const float*)d_in[8];
    const float* b3  = (const float*)d_in[9];
    float* out = (float*)d_out;

    float* W = (float*)d_ws;
    // [0 .. 4,194,304) f32: P01 fp16 corr partials (8.4M ush); aliased by
    //   attfq fp32 (2.1M, post-softmax)
    unsigned short* P01u = (unsigned short*)W;
    float* attfq = W;
    // [4,194,304 .. 6,553,600): attn fp16 padded (4.7M ush); aliased by w1p
    //   (2.95M ush, dead after conv1m), rq/rs (written by k_prep after conv1m,
    //   dead after k_corr2, overwritten by k_softmax's attn), w2p (post-attn)
    unsigned short* attn = (unsigned short*)(W + 4194304);
    unsigned short* w1p  = (unsigned short*)(W + 4194304);
    float* rq = W + 5668864;   // after w1p span; 36864 floats
    float* rs = W + 5705728;   // 36864 floats; ends 5,742,592 < attn end
    unsigned short* w2p  = (unsigned short*)(W + 4194304);
    // [6,553,600 .. 7,733,248): fs fp16 padded (2.36M ush)
    unsigned short* fsp = (unsigned short*)(W + 6553600);
    // [7,733,248 .. 8,257,536): x1 bf16 (1.05M ush)
    unsigned short* x1 = (unsigned short*)(W + 7733248);
    // [8,257,536 .. 8,359,936): xp fp32
    float* xp = W + 8257536;
    // [8,359,936 .. 17,797,120): fqb f16 tiles; aliased by conv partials P9
    //   (9,437,184 floats exactly) — P9 used only while fqb is dead
    unsigned short* fqb = (unsigned short*)(W + 8359936);
    float* P9 = W + 8359936;
    // [17,797,120 .. 27,234,304): fsb f16 tiles
    unsigned short* fsb = (unsigned short*)(W + 17797120);

    // conv1 phase (w1p in attn region, P9 in fqb region — both dead later)
    hipLaunchKernelGGL(k_w1pack,  dim3(1024),      dim3(256), 0, stream, w1, w1p);
    hipLaunchKernelGGL(k_conv1m,  dim3(16, 4, 9),  dim3(256), 0, stream, fqi, fsi, w1p, P9);
    hipLaunchKernelGGL(k_c1comb,  dim3(1024),      dim3(256), 0, stream, P9, b1, x1);
    hipLaunchKernelGGL(k_fspack,  dim3(256),       dim3(256), 0, stream, fsi, fsp);
    // attention path
    hipLaunchKernelGGL(k_prep,    dim3(8, 36, 2),  dim3(256), 0, stream, fqf, fsf, fqb, fsb, rq, rs);
    hipLaunchKernelGGL(k_corr2,   dim3(512),       dim3(256), 0, stream, fqb, fsb, rq, rs, P01u);
    hipLaunchKernelGGL(k_softmax, dim3(4096),      dim3(256), 0, stream, P01u, attn);
    hipLaunchKernelGGL(k_attfqm,  dim3(8, 8, 4),   dim3(256), 0, stream, fsp, attn, attfq);
    hipLaunchKernelGGL(k_out,     dim3(16, 4),     dim3(256), 0, stream, fqi, attfq, out);
    // conv tail (w2p in attn region, P9 in fqb region — dead after k_out/corr2)
    hipLaunchKernelGGL(k_w2pack,  dim3(256),       dim3(256), 0, stream, w2, w2p);
    hipLaunchKernelGGL(k_conv2m,  dim3(16, 4, 9),  dim3(256), 0, stream, x1, w2p, P9);
    hipLaunchKernelGGL(k_c2pool,  dim3(400),       dim3(256), 0, stream, P9, b2, xp);
    hipLaunchKernelGGL(k_conv3,   dim3(4),         dim3(256), 0, stream, xp, w3, b3, out);
}

// Round 4
// 422.986 us; speedup vs baseline: 1.3695x; 1.0661x over previous
//
#include <hip/hip_runtime.h>
#include <hip/hip_bf16.h>

#define DI __device__ __forceinline__

typedef short bf16x8_t __attribute__((ext_vector_type(8)));
typedef _Float16 f16x8_t __attribute__((ext_vector_type(8)));
typedef float f32x4_t __attribute__((ext_vector_type(4)));

DI unsigned short f2bf(float f) {
    unsigned u = __float_as_uint(f);
    u += 0x7fffu + ((u >> 16) & 1u);
    return (unsigned short)(u >> 16);
}
DI float bfu2f(unsigned short u) { return __uint_as_float(((unsigned)u) << 16); }
DI unsigned short f2h(float f) {
    _Float16 h = (_Float16)f;
    unsigned short u;
    __builtin_memcpy(&u, &h, 2);
    return u;
}
DI float h2f(unsigned short u) {
    _Float16 h;
    __builtin_memcpy(&h, &u, 2);
    return (float)h;
}

// ---------------------------------------------------------------------------
// Kernel 1b (v3): transpose/convert to raw f16 tiles + partial ssq.
// grid (8 ptile, 36 lb, 8 = tz*4+kg) x 256; each block does 4 ks-steps with
// double-buffered LDS T (1 barrier/step; loads issued post-barrier hide under
// phase C). Partial per-pos sum-of-squares (128 ch) -> rpart[tz][kg][36864];
// k_rfold folds 4 partials -> rq/rs inverse norms.
// ---------------------------------------------------------------------------
__global__ __launch_bounds__(256) void k_prep(const float* __restrict__ fqf,
                                              const float* __restrict__ fsf,
                                              unsigned short* __restrict__ fqb,
                                              unsigned short* __restrict__ fsb,
                                              float* __restrict__ rpart) {
    __shared__ float T[2][128 * 33];   // [buf][pos][33]
    const int pt = blockIdx.x;
    const int lb = blockIdx.y;
    const int zz = blockIdx.z;
    const int tz = zz >> 2, kg = zz & 3;
    const int ks0 = kg * 4;
    const float* src = (tz ? fsf : fqf) + (size_t)lb * 524288 + pt * 128;
    unsigned short* dst = (tz ? fsb : fqb) + (((size_t)(lb * 8 + pt)) << 16);
    float* rdst = rpart + (size_t)tz * 147456 + (size_t)kg * 36864 + lb * 1024 + pt * 128;
    const int t = threadIdx.x;

    // phase-C per-thread constants (2 chunks: c = t and t+256)
    const int m0 = t >> 2, m1 = 64 + (t >> 2);
    const int q0 = (t & 3) ^ ((m0 >> 2) & 3);
    const int q1 = (t & 3) ^ ((m1 >> 2) & 3);
    float ssq0 = 0.f, ssq1 = 0.f;

    float4 v[4];
    auto load = [&](int ks) {
#pragma unroll
        for (int j = 0; j < 4; ++j) {
            int f = t + (j << 8);
            int row = f >> 5;
            int m4 = (f & 31) << 2;
            v[j] = *(const float4*)(src + (((size_t)(ks * 32 + row)) << 10) + m4);
        }
    };
    auto writeT = [&](int buf) {
#pragma unroll
        for (int j = 0; j < 4; ++j) {
            int f = t + (j << 8);
            int row = f >> 5;
            int m4 = (f & 31) << 2;
            float* Tb = &T[buf][0];
            Tb[(m4 + 0) * 33 + row] = v[j].x;
            Tb[(m4 + 1) * 33 + row] = v[j].y;
            Tb[(m4 + 2) * 33 + row] = v[j].z;
            Tb[(m4 + 3) * 33 + row] = v[j].w;
        }
    };

    load(ks0);
    writeT(0);
    for (int s = 0; s < 4; ++s) {
        __syncthreads();                 // T[s&1] ready; prev reads of T[s&1^1] done
        if (s < 3) load(ks0 + s + 1);    // async issue; hidden under phase C
        const int ks = ks0 + s;
        const float* Tb = &T[s & 1][0];
        // phase C: read T, convert raw f16, swizzled chunk writes, accum ssq
        {
            const float* Tp = Tb + m0 * 33 + q0 * 8;
            float f0 = Tp[0], f1 = Tp[1], f2 = Tp[2], f3 = Tp[3];
            float f4 = Tp[4], f5 = Tp[5], f6 = Tp[6], f7 = Tp[7];
            ssq0 += f0 * f0 + f1 * f1 + f2 * f2 + f3 * f3 +
                    f4 * f4 + f5 * f5 + f6 * f6 + f7 * f7;
            uint4 r4;
            r4.x = (unsigned)f2h(f0) | ((unsigned)f2h(f1) << 16);
            r4.y = (unsigned)f2h(f2) | ((unsigned)f2h(f3) << 16);
            r4.z = (unsigned)f2h(f4) | ((unsigned)f2h(f5) << 16);
            r4.w = (unsigned)f2h(f6) | ((unsigned)f2h(f7) << 16);
            *(uint4*)(dst + ((size_t)ks << 12) + ((size_t)t << 3)) = r4;
        }
        {
            const float* Tp = Tb + m1 * 33 + q1 * 8;
            float f0 = Tp[0], f1 = Tp[1], f2 = Tp[2], f3 = Tp[3];
            float f4 = Tp[4], f5 = Tp[5], f6 = Tp[6], f7 = Tp[7];
            ssq1 += f0 * f0 + f1 * f1 + f2 * f2 + f3 * f3 +
                    f4 * f4 + f5 * f5 + f6 * f6 + f7 * f7;
            uint4 r4;
            r4.x = (unsigned)f2h(f0) | ((unsigned)f2h(f1) << 16);
            r4.y = (unsigned)f2h(f2) | ((unsigned)f2h(f3) << 16);
            r4.z = (unsigned)f2h(f4) | ((unsigned)f2h(f5) << 16);
            r4.w = (unsigned)f2h(f6) | ((unsigned)f2h(f7) << 16);
            *(uint4*)(dst + ((size_t)ks << 12) + ((size_t)(t + 256) << 3)) = r4;
        }
        if (s < 3) writeT((s + 1) & 1);  // waits loads; overlap already consumed
    }
    // reduce ssq across the 4 lanes sharing each position
    ssq0 += __shfl_xor(ssq0, 1); ssq0 += __shfl_xor(ssq0, 2);
    ssq1 += __shfl_xor(ssq1, 1); ssq1 += __shfl_xor(ssq1, 2);
    if ((t & 3) == 0) {
        rdst[m0] = ssq0;
        rdst[m1] = ssq1;
    }
}

// ---------------------------------------------------------------------------
// Kernel 1c: fold 4 ssq partials -> inverse norms. rout = [rq | rs] contiguous.
// ---------------------------------------------------------------------------
__global__ __launch_bounds__(256) void k_rfold(const float* __restrict__ rpart,
                                               float* __restrict__ rout) {
    int id = blockIdx.x * 256 + threadIdx.x;   // 0..73727
    int tz = id >= 36864;
    int i = id - (tz ? 36864 : 0);
    const float* p = rpart + (size_t)tz * 147456 + i;
    float s = p[0] + p[36864] + p[73728] + p[110592];
    rout[id] = 1.f / fmaxf(sqrtf(s), 1e-12f);
}

// ---------------------------------------------------------------------------
// Kernel 2b (raw f16 tiles): corr partials, 2-way level split. Normalization
// (rq*rs) applied in the per-level ReLU epilogue.
// ---------------------------------------------------------------------------
__global__ __launch_bounds__(256) void k_corr2(const unsigned short* __restrict__ fqb,
                                               const unsigned short* __restrict__ fsb,
                                               const float* __restrict__ rq,
                                               const float* __restrict__ rs,
                                               unsigned short* __restrict__ P01) {
    __shared__ __align__(16) char L[2][16384];   // A 8 KB | B 8 KB per buf
    const int id = blockIdx.x;
    const int z = id & 7, local = id >> 3;       // z -> XCD-resident (b,lg)
    const int b = z >> 1, lg = z & 1;
    const int qt = local >> 3, st = local & 7;
    const int q0 = qt * 128, s0 = st * 128;
    const int t = threadIdx.x;
    const int w = t >> 6, lane = t & 63;
    const int wrow = w >> 1, wcol = w & 1;
    const int quad = lane >> 4, m16 = lane & 15;
    const int nsteps = (5 - lg) << 4;            // lg0: 80, lg1: 64

    f32x4_t zero4 = {0.f, 0.f, 0.f, 0.f};
    f32x4_t master[4][4], lvl[4][4];
#pragma unroll
    for (int i = 0; i < 4; ++i)
#pragma unroll
        for (int j = 0; j < 4; ++j) { master[i][j] = zero4; lvl[i][j] = zero4; }

    auto stage = [&](int step, int buf) {
        int g = step >> 4, ks = step & 15;
        int lb = (lg + 2 * g) * 4 + b;
        const unsigned short* Ab = fqb + ((((size_t)lb * 8 + qt) * 16 + ks) << 12);
        const unsigned short* Bb = fsb + ((((size_t)lb * 8 + st) * 16 + ks) << 12);
#pragma unroll
        for (int i = 0; i < 4; ++i) {
            int idx0 = i * 256 + w * 64;   // wave-uniform; A:0..511, B:512..1023
            int idx = idx0 + lane;
            const unsigned short* srcp = (idx0 < 512)
                ? (Ab + ((size_t)idx << 3))
                : (Bb + ((size_t)(idx - 512) << 3));
            __builtin_amdgcn_global_load_lds(
                (const __attribute__((address_space(1))) void*)srcp,
                (__attribute__((address_space(3))) void*)(&L[buf][0] + idx0 * 16),
                16, 0, 0);
        }
    };

    stage(0, 0);
    for (int step = 0; step < nsteps; ++step) {
        const int buf = step & 1;
        __syncthreads();
        if (step < nsteps - 1) stage(step + 1, buf ^ 1);
        const char* base = &L[buf][0];
        f16x8_t af[4], bfr[4];
#pragma unroll
        for (int i = 0; i < 4; ++i) {
            int m = wrow * 64 + i * 16 + m16;
            int sa = quad ^ ((m >> 2) & 3);
            af[i] = *(const f16x8_t*)(base + m * 64 + sa * 16);
            int n = wcol * 64 + i * 16 + m16;
            int sb = quad ^ ((n >> 2) & 3);
            bfr[i] = *(const f16x8_t*)(base + 8192 + n * 64 + sb * 16);
        }
#pragma unroll
        for (int mi = 0; mi < 4; ++mi)
#pragma unroll
            for (int ni = 0; ni < 4; ++ni)
                lvl[mi][ni] = __builtin_amdgcn_mfma_f32_16x16x32_f16(
                    af[mi], bfr[ni], lvl[mi][ni], 0, 0, 0);

        if ((step & 15) == 15) {   // end of a level: normalize + ReLU + accum
            int lb = (lg + 2 * (step >> 4)) * 4 + b;
            const float* rqb = rq + lb * 1024 + q0 + wrow * 64;
            const float* rsb = rs + lb * 1024 + s0 + wcol * 64;
            float rq4[4][4], rsv[4];
#pragma unroll
            for (int mi = 0; mi < 4; ++mi) {
                float4 vv = *(const float4*)(rqb + mi * 16 + quad * 4);
                rq4[mi][0] = vv.x; rq4[mi][1] = vv.y; rq4[mi][2] = vv.z; rq4[mi][3] = vv.w;
            }
#pragma unroll
            for (int ni = 0; ni < 4; ++ni) rsv[ni] = rsb[ni * 16 + m16];
#pragma unroll
            for (int mi = 0; mi < 4; ++mi)
#pragma unroll
                for (int ni = 0; ni < 4; ++ni) {
#pragma unroll
                    for (int e = 0; e < 4; ++e)
                        master[mi][ni][e] += fmaxf(lvl[mi][ni][e] * rq4[mi][e] * rsv[ni], 0.f);
                    lvl[mi][ni] = zero4;
                }
        }
    }

#pragma unroll
    for (int mi = 0; mi < 4; ++mi)
#pragma unroll
        for (int e = 0; e < 4; ++e) {
            int q = q0 + wrow * 64 + mi * 16 + quad * 4 + e;
            unsigned short* cp = P01 + ((((size_t)(lg * 4 + b)) * 1024 + q) << 10)
                                 + s0 + wcol * 64 + m16;
#pragma unroll
            for (int ni = 0; ni < 4; ++ni)
                cp[ni * 16] = f2h(master[mi][ni][e]);
        }
}

// ---------------------------------------------------------------------------
// Kernel 3: softmax over s. Reads 2 fp16 partials, scale 20/9, writes attn as
// padded fp16 [b][sb(32)][q][36] for MFMA staging.
// ---------------------------------------------------------------------------
__global__ __launch_bounds__(256) void k_softmax(const unsigned short* __restrict__ P01,
                                                 unsigned short* __restrict__ attn) {
    __shared__ float red[8];
    const int row = blockIdx.x;  // 0..4095
    const int b = row >> 10, q = row & 1023;
    const int t = threadIdx.x;
    const unsigned short* p0 = P01 + (((size_t)b << 20) + ((size_t)q << 10)) + t * 4;
    const unsigned short* p1 = p0 + ((size_t)4 << 20);
    uint2 a0 = *(const uint2*)p0;
    uint2 a1 = *(const uint2*)p1;
    const float SC = 20.f / 9.f;
    float v0 = (h2f(a0.x & 0xffff) + h2f(a1.x & 0xffff)) * SC;
    float v1 = (h2f(a0.x >> 16)    + h2f(a1.x >> 16)) * SC;
    float v2 = (h2f(a0.y & 0xffff) + h2f(a1.y & 0xffff)) * SC;
    float v3 = (h2f(a0.y >> 16)    + h2f(a1.y >> 16)) * SC;
    float m = fmaxf(fmaxf(v0, v1), fmaxf(v2, v3));
#pragma unroll
    for (int off = 32; off >= 1; off >>= 1) m = fmaxf(m, __shfl_down(m, off));
    const int wid = t >> 6, lane = t & 63;
    if (lane == 0) red[wid] = m;
    __syncthreads();
    m = fmaxf(fmaxf(red[0], red[1]), fmaxf(red[2], red[3]));
    float e0 = __expf(v0 - m), e1 = __expf(v1 - m);
    float e2 = __expf(v2 - m), e3 = __expf(v3 - m);
    float s = e0 + e1 + e2 + e3;
#pragma unroll
    for (int off = 32; off >= 1; off >>= 1) s += __shfl_down(s, off);
    if (lane == 0) red[4 + wid] = s;
    __syncthreads();
    s = red[4] + red[5] + red[6] + red[7];
    float inv = 1.f / s;
    unsigned short* o = attn + (size_t)((b * 32 + (t >> 3)) * 1024 + q) * 36 + (t & 7) * 4;
    uint2 r;
    r.x = (unsigned)f2h(e0 * inv) | ((unsigned)f2h(e1 * inv) << 16);
    r.y = (unsigned)f2h(e2 * inv) | ((unsigned)f2h(e3 * inv) << 16);
    *(uint2*)o = r;
}

// ---------------------------------------------------------------------------
// Kernel 4a: pack f_s fp32 [b][c][s] -> fp16 [b][sb(32)][c][36]
// ---------------------------------------------------------------------------
__global__ __launch_bounds__(256) void k_fspack(const float* __restrict__ fsi,
                                                unsigned short* __restrict__ fsp) {
    int id = blockIdx.x * 256 + threadIdx.x;  // 0..65535
    int c = id & 511, sb = (id >> 9) & 31, b = id >> 14;
    const float4* src = (const float4*)(fsi + (((size_t)(b * 512 + c)) << 10) + sb * 32);
    unsigned short* dst = fsp + (size_t)((b * 32 + sb) * 512 + c) * 36;
#pragma unroll
    for (int j = 0; j < 8; ++j) {
        float4 v = src[j];
        uint2 r;
        r.x = (unsigned)f2h(v.x) | ((unsigned)f2h(v.y) << 16);
        r.y = (unsigned)f2h(v.z) | ((unsigned)f2h(v.w) << 16);
        *(uint2*)(dst + j * 4) = r;
    }
}

// ---------------------------------------------------------------------------
// Kernel 4b (MFMA f16): att_fq[b,c,q] = sum_s attn[q,s] * f_s[c,s]
// ---------------------------------------------------------------------------
__global__ __launch_bounds__(256) void k_attfqm(const unsigned short* __restrict__ fsp,
                                                const unsigned short* __restrict__ attn,
                                                float* __restrict__ attfq) {
    __shared__ __align__(16) char L[2][14336];  // A 4608 B | B 9216 B | pad 512
    const int q0 = blockIdx.x * 128;
    const int c0 = blockIdx.y * 64;
    const int b  = blockIdx.z;
    const int t = threadIdx.x;
    const int w = t >> 6, lane = t & 63;
    const int quad = lane >> 4, m16 = lane & 15;

    f32x4_t acc[4][2];
#pragma unroll
    for (int i = 0; i < 4; ++i)
#pragma unroll
        for (int j = 0; j < 2; ++j) acc[i][j] = (f32x4_t){0.f, 0.f, 0.f, 0.f};

    auto stage = [&](int sb, int buf) {
        const char* sa = (const char*)(fsp + (size_t)((b * 32 + sb) * 512 + c0) * 36);
        const char* sbp = (const char*)(attn + (size_t)((b * 32 + sb) * 1024 + q0) * 36);
#pragma unroll
        for (int i = 0; i < 4; ++i) {
            int idx0 = i * 256 + w * 64;          // wave-uniform chunk base
            if (idx0 < 896) {                      // uniform predicate (pad reads ok)
                int idx = idx0 + lane;
                const char* src = (idx < 288) ? (sa + idx * 16) : (sbp + (idx - 288) * 16);
                __builtin_amdgcn_global_load_lds(
                    (const __attribute__((address_space(1))) void*)src,
                    (__attribute__((address_space(3))) void*)(&L[buf][0] + idx0 * 16),
                    16, 0, 0);
            }
        }
    };

    stage(0, 0);
    for (int sb = 0; sb < 32; ++sb) {
        const int buf = sb & 1;
        __syncthreads();
        if (sb < 31) stage(sb + 1, buf ^ 1);
        const char* base = &L[buf][0];
        f16x8_t af[4], bfr[2];
#pragma unroll
        for (int i = 0; i < 4; ++i) {
            const char* ap = base + (size_t)(i * 16 + m16) * 72 + quad * 16;
            union { unsigned long long d[2]; f16x8_t v; } u;
            u.d[0] = *(const unsigned long long*)ap;
            u.d[1] = *(const unsigned long long*)(ap + 8);
            af[i] = u.v;
        }
#pragma unroll
        for (int ni = 0; ni < 2; ++ni) {
            const char* bp = base + 4608 + (size_t)(w * 32 + ni * 16 + m16) * 72 + quad * 16;
            union { unsigned long long d[2]; f16x8_t v; } u;
            u.d[0] = *(const unsigned long long*)bp;
            u.d[1] = *(const unsigned long long*)(bp + 8);
            bfr[ni] = u.v;
        }
#pragma unroll
        for (int mi = 0; mi < 4; ++mi)
#pragma unroll
            for (int ni = 0; ni < 2; ++ni)
                acc[mi][ni] = __builtin_amdgcn_mfma_f32_16x16x32_f16(
                    af[mi], bfr[ni], acc[mi][ni], 0, 0, 0);
    }

#pragma unroll
    for (int mi = 0; mi < 4; ++mi)
#pragma unroll
        for (int e = 0; e < 4; ++e) {
            int c = c0 + mi * 16 + quad * 4 + e;
            float* rowp = attfq + (((size_t)(b * 512 + c)) << 10) + q0 + w * 32 + m16;
#pragma unroll
            for (int ni = 0; ni < 2; ++ni)
                rowp[ni * 16] = acc[mi][ni][e];
        }
}

// ---------------------------------------------------------------------------
// Kernel 5 (v2, 256 blocks): fq = l2n(f_q,C) + 0.5*l2n(att_fq,C).
// grid (64, 4): 16 positions/block, 16 channel-groups of 32.
// ---------------------------------------------------------------------------
__global__ __launch_bounds__(256) void k_out(const float* __restrict__ fqi,
                                             const float* __restrict__ attfq,
                                             float* __restrict__ out) {
    __shared__ float redq[256], reda[256];
    __shared__ float rnq[16], rna[16];
    const int b = blockIdx.y;
    const int p0 = blockIdx.x * 16;
    const int t = threadIdx.x;
    const int pl = t & 15, cg = t >> 4;
    const int pos = p0 + pl;
    const float* qp = fqi + (((size_t)b) << 19) + pos;
    const float* ap = attfq + (((size_t)b) << 19) + pos;
    float sq = 0.f, sa = 0.f;
    for (int c = cg * 32; c < cg * 32 + 32; ++c) {
        float q = qp[(size_t)c << 10];
        float a = ap[(size_t)c << 10];
        sq += q * q;
        sa += a * a;
    }
    redq[t] = sq; reda[t] = sa;
    __syncthreads();
    if (t < 16) {
        float q = 0.f, a = 0.f;
#pragma unroll
        for (int j = 0; j < 16; ++j) { q += redq[t + j * 16]; a += reda[t + j * 16]; }
        rnq[t] = 1.f / fmaxf(sqrtf(q), 1e-12f);
        rna[t] = 0.5f / fmaxf(sqrtf(a), 1e-12f);
    }
    __syncthreads();
    const float RQ = rnq[pl], RA = rna[pl];
    float* o1 = out + (((size_t)b) << 19) + pos;
    float* o2 = o1 + 2097152;
    for (int c = cg * 32; c < cg * 32 + 32; ++c) {
        float q = qp[(size_t)c << 10];
        float a = ap[(size_t)c << 10];
        o1[(size_t)c << 10] = q * RQ + a * RA;
        o2[(size_t)c << 10] = a;
    }
}

// ---------------------------------------------------------------------------
// Kernel 6a: pack w1 fp32 [256 oc][1024 ic][9 tap] -> bf16 [tap][s(32)][oc][40]
// ---------------------------------------------------------------------------
__global__ __launch_bounds__(256) void k_w1pack(const float* __restrict__ w1,
                                                unsigned short* __restrict__ w1p) {
    int pid = blockIdx.x * 256 + threadIdx.x;  // 0..262143 = (oc,ic)
    int oc = pid >> 10, ic = pid & 1023;
    const float* src = w1 + (size_t)pid * 9;
    float f[9];
#pragma unroll
    for (int tp = 0; tp < 9; ++tp) f[tp] = src[tp];
    int s = ic >> 5, j = ic & 31;
#pragma unroll
    for (int tp = 0; tp < 9; ++tp) {
        size_t row = ((size_t)(tp * 32 + s) * 256 + oc) * 40;
        w1p[row + j] = f2bf(f[tp]);
        if (j < 8) w1p[row + 32 + j] = 0;
    }
}

// ---------------------------------------------------------------------------
// Kernel 6b (MFMA): conv1 partials, one tap per block-z (9-way K split).
// grid (16 pos-tiles, 4 b, 9 tap). 32 K-steps of BK=32 channels.
// ---------------------------------------------------------------------------
__global__ __launch_bounds__(256) void k_conv1m(const float* __restrict__ fqi,
                                                const float* __restrict__ fsi,
                                                const unsigned short* __restrict__ w1p,
                                                float* __restrict__ P) {
    __shared__ __align__(16) char As[2][20480];   // [buf][256 oc][40 bf16]
    __shared__ __align__(16) char Bs[2][4096];    // [buf][64 n][32 k] bf16 swz
    const int p0 = blockIdx.x * 64;
    const int b = blockIdx.y;
    const int tap = blockIdx.z;                   // kh*3+kw
    const int dy = 2 * (tap / 3) - 2;
    const int dx = 2 * (tap % 3) - 2;
    const int t = threadIdx.x;
    const int w = t >> 6, lane = t & 63;
    const int quad = lane >> 4, m16 = lane & 15;
    const int bn = t & 63, kg = t >> 6;
    const int e0 = p0 + bn;
    const bool valid = ((unsigned)((e0 >> 5) + dy) < 32u) &&
                       ((unsigned)((e0 & 31) + dx) < 32u);
    const int cidx = min(max(e0 + dy * 32 + dx, 0), 1023);
    const int bchunk = (bn * 4 + (kg ^ (bn & 3))) * 16;

    f32x4_t acc[4][4];
#pragma unroll
    for (int i = 0; i < 4; ++i)
#pragma unroll
        for (int j = 0; j < 4; ++j) acc[i][j] = (f32x4_t){0.f, 0.f, 0.f, 0.f};

    auto stageA = [&](int s, int buf) {
        const char* src = (const char*)(w1p + (size_t)(tap * 32 + s) * 10240);
#pragma unroll
        for (int i = 0; i < 5; ++i) {
            int idx = i * 4 + w;
            __builtin_amdgcn_global_load_lds(
                (const __attribute__((address_space(1))) void*)(src + idx * 1024 + lane * 16),
                (__attribute__((address_space(3))) void*)(&As[buf][0] + idx * 1024),
                16, 0, 0);
        }
    };
    auto stageB = [&](int s, int buf) {
        int ch = s * 32 + kg * 8;                 // 8-ch group never straddles 512
        const float* plane = (ch < 512)
            ? (fqi + (((size_t)(b * 512 + ch)) << 10))
            : (fsi + (((size_t)(b * 512 + ch - 512)) << 10));
        float f[8];
#pragma unroll
        for (int j = 0; j < 8; ++j) {
            float v = plane[((size_t)j << 10) + cidx];
            f[j] = valid ? v : 0.f;
        }
        uint4 r4;
        r4.x = (unsigned)f2bf(f[0]) | ((unsigned)f2bf(f[1]) << 16);
        r4.y = (unsigned)f2bf(f[2]) | ((unsigned)f2bf(f[3]) << 16);
        r4.z = (unsigned)f2bf(f[4]) | ((unsigned)f2bf(f[5]) << 16);
        r4.w = (unsigned)f2bf(f[6]) | ((unsigned)f2bf(f[7]) << 16);
        *(uint4*)(&Bs[buf][bchunk]) = r4;
    };

    stageA(0, 0);
    stageB(0, 0);

    for (int s = 0; s < 32; ++s) {
        const int buf = s & 1;
        __syncthreads();
        if (s < 31) {
            stageA(s + 1, buf ^ 1);
            stageB(s + 1, buf ^ 1);
        }
        bf16x8_t af[4], bfr[4];
#pragma unroll
        for (int i = 0; i < 4; ++i) {
            af[i] = *(const bf16x8_t*)(&As[buf][0] + (size_t)(w * 64 + i * 16 + m16) * 80 + quad * 16);
            int nn = i * 16 + m16;
            bfr[i] = *(const bf16x8_t*)(&Bs[buf][0] + (nn * 4 + (quad ^ (nn & 3))) * 16);
        }
#pragma unroll
        for (int mi = 0; mi < 4; ++mi)
#pragma unroll
            for (int ni = 0; ni < 4; ++ni)
                acc[mi][ni] = __builtin_amdgcn_mfma_f32_16x16x32_bf16(
                    af[mi], bfr[ni], acc[mi][ni], 0, 0, 0);
    }

    float* Pb = P + (((size_t)(tap * 4 + b)) << 18) + p0;
#pragma unroll
    for (int mi = 0; mi < 4; ++mi)
#pragma unroll
        for (int e = 0; e < 4; ++e) {
            int oc = w * 64 + mi * 16 + quad * 4 + e;
            float* row = Pb + (size_t)oc * 1024 + m16;
#pragma unroll
            for (int ni = 0; ni < 4; ++ni)
                row[ni * 16] = acc[mi][ni][e];
        }
}

// ---------------------------------------------------------------------------
// Kernel 6c: x1 = relu(sum of 9 partials + b1), stored bf16
// ---------------------------------------------------------------------------
__global__ __launch_bounds__(256) void k_c1comb(const float* __restrict__ P,
                                                const float* __restrict__ b1,
                                                unsigned short* __restrict__ x1) {
    int id = blockIdx.x * 256 + threadIdx.x;  // 4-elem index, 0..262143
    int oc = (id >> 8) & 255;
    const float4* P4 = (const float4*)P;
    float bb = b1[oc];
    float4 a = P4[id];
    a.x += bb; a.y += bb; a.z += bb; a.w += bb;
#pragma unroll
    for (int tp = 1; tp < 9; ++tp) {
        float4 v = P4[id + tp * 262144];
        a.x += v.x; a.y += v.y; a.z += v.z; a.w += v.w;
    }
    float o0 = fmaxf(a.x, 0.f);
    float o1 = fmaxf(a.y, 0.f);
    float o2 = fmaxf(a.z, 0.f);
    float o3 = fmaxf(a.w, 0.f);
    uint2 r;
    r.x = (unsigned)f2bf(o0) | ((unsigned)f2bf(o1) << 16);
    r.y = (unsigned)f2bf(o2) | ((unsigned)f2bf(o3) << 16);
    ((uint2*)x1)[id] = r;
}

// ---------------------------------------------------------------------------
// Kernel 7a: pack w2 fp32 [256 oc][256 ic][9 tap] -> bf16 [tap][s(8)][oc][40]
// ---------------------------------------------------------------------------
__global__ __launch_bounds__(256) void k_w2pack(const float* __restrict__ w2,
                                                unsigned short* __restrict__ w2p) {
    int pid = blockIdx.x * 256 + threadIdx.x;  // 0..65535 = (oc,ic)
    int oc = pid >> 8, ic = pid & 255;
    const float* src = w2 + (size_t)pid * 9;
    float f[9];
#pragma unroll
    for (int tp = 0; tp < 9; ++tp) f[tp] = src[tp];
    int s = ic >> 5, j = ic & 31;
#pragma unroll
    for (int tp = 0; tp < 9; ++tp) {
        size_t row = ((size_t)(tp * 8 + s) * 256 + oc) * 40;
        w2p[row + j] = f2bf(f[tp]);
        if (j < 8) w2p[row + 32 + j] = 0;
    }
}

// ---------------------------------------------------------------------------
// Kernel 7b (MFMA): conv2 partials, one tap per block-z (x1 bf16 input).
// grid (16, 4, 9). 8 K-steps of BK=32.
// ---------------------------------------------------------------------------
__global__ __launch_bounds__(256) void k_conv2m(const unsigned short* __restrict__ x1,
                                                const unsigned short* __restrict__ w2p,
                                                float* __restrict__ P2) {
    __shared__ __align__(16) char As[2][20480];   // [buf][256 oc][40 bf16]
    __shared__ __align__(16) char Bs[2][4096];    // [buf][64 n][32 k] bf16 swz
    const int p0 = blockIdx.x * 64;
    const int b = blockIdx.y;
    const int tap = blockIdx.z;                   // kh*3+kw
    const int t = threadIdx.x;
    const int w = t >> 6, lane = t & 63;
    const int quad = lane >> 4, m16 = lane & 15;
    const int bn = t & 63, kg = t >> 6;
    const int e0 = p0 + bn;
    const int cidx = min(e0 + (tap / 3) * 32 + (tap % 3), 1023);
    const int bchunk = (bn * 4 + (kg ^ (bn & 3))) * 16;

    f32x4_t acc[4][4];
#pragma unroll
    for (int i = 0; i < 4; ++i)
#pragma unroll
        for (int j = 0; j < 4; ++j) acc[i][j] = (f32x4_t){0.f, 0.f, 0.f, 0.f};

    auto stageA = [&](int s, int buf) {
        const char* src = (const char*)(w2p + (size_t)(tap * 8 + s) * 10240);
#pragma unroll
        for (int i = 0; i < 5; ++i) {
            int idx = i * 4 + w;
            __builtin_amdgcn_global_load_lds(
                (const __attribute__((address_space(1))) void*)(src + idx * 1024 + lane * 16),
                (__attribute__((address_space(3))) void*)(&As[buf][0] + idx * 1024),
                16, 0, 0);
        }
    };
    auto stageB = [&](int s, int buf) {
        int ch = s * 32 + kg * 8;
        const unsigned short* plane = x1 + (((size_t)(b * 256 + ch)) << 10);
        unsigned short u[8];
#pragma unroll
        for (int j = 0; j < 8; ++j) u[j] = plane[((size_t)j << 10) + cidx];
        uint4 r4;
        r4.x = (unsigned)u[0] | ((unsigned)u[1] << 16);
        r4.y = (unsigned)u[2] | ((unsigned)u[3] << 16);
        r4.z = (unsigned)u[4] | ((unsigned)u[5] << 16);
        r4.w = (unsigned)u[6] | ((unsigned)u[7] << 16);
        *(uint4*)(&Bs[buf][bchunk]) = r4;
    };

    stageA(0, 0);
    stageB(0, 0);

    for (int s = 0; s < 8; ++s) {
        const int buf = s & 1;
        __syncthreads();
        if (s < 7) {
            stageA(s + 1, buf ^ 1);
            stageB(s + 1, buf ^ 1);
        }
        bf16x8_t af[4], bfr[4];
#pragma unroll
        for (int i = 0; i < 4; ++i) {
            af[i] = *(const bf16x8_t*)(&As[buf][0] + (size_t)(w * 64 + i * 16 + m16) * 80 + quad * 16);
            int nn = i * 16 + m16;
            bfr[i] = *(const bf16x8_t*)(&Bs[buf][0] + (nn * 4 + (quad ^ (nn & 3))) * 16);
        }
#pragma unroll
        for (int mi = 0; mi < 4; ++mi)
#pragma unroll
            for (int ni = 0; ni < 4; ++ni)
                acc[mi][ni] = __builtin_amdgcn_mfma_f32_16x16x32_bf16(
                    af[mi], bfr[ni], acc[mi][ni], 0, 0, 0);
    }

    float* Pb = P2 + (((size_t)(tap * 4 + b)) << 18) + p0;
#pragma unroll
    for (int mi = 0; mi < 4; ++mi)
#pragma unroll
        for (int e = 0; e < 4; ++e) {
            int oc = w * 64 + mi * 16 + quad * 4 + e;
            float* row = Pb + (size_t)oc * 1024 + m16;
#pragma unroll
            for (int ni = 0; ni < 4; ++ni)
                row[ni * 16] = acc[mi][ni][e];
        }
}

// ---------------------------------------------------------------------------
// Kernel 7c: combine 9 conv2 partials + bias, then 3x3/3 maxpool -> xp[4][256][100]
// ---------------------------------------------------------------------------
__global__ __launch_bounds__(256) void k_c2pool(const float* __restrict__ P2,
                                                const float* __restrict__ b2,
                                                float* __restrict__ xp) {
    int id = blockIdx.x * 256 + threadIdx.x;  // 0..102399
    int px = id % 10;
    int tmp = id / 10;
    int py = tmp % 10;
    int ch = tmp / 10;          // b*256 + oc
    int b = ch >> 8, oc = ch & 255;
    float bb = b2[oc];
    float m = -3.4e38f;
#pragma unroll
    for (int dy = 0; dy < 3; ++dy)
#pragma unroll
        for (int dx = 0; dx < 3; ++dx) {
            int pos = (3 * py + dy) * 32 + 3 * px + dx;
            float v = bb;
#pragma unroll
            for (int tp = 0; tp < 9; ++tp)
                v += P2[(((size_t)(tp * 4 + b)) << 18) + (size_t)oc * 1024 + pos];
            m = fmaxf(m, v);
        }
    xp[id] = m;
}

// ---------------------------------------------------------------------------
// Kernel 9: conv3 (256ch, 10x10 -> 8x8) + spatial mean + b3 -> weight[1,B]
// ---------------------------------------------------------------------------
__global__ __launch_bounds__(256) void k_conv3(const float* __restrict__ xp,
                                               const float* __restrict__ w3,
                                               const float* __restrict__ b3,
                                               float* __restrict__ out) {
    __shared__ float s[256];
    int b = blockIdx.x, t = threadIdx.x;
    int pos = t & 63, qi = t >> 6;
    int y = pos >> 3, x = pos & 7;
    float acc = 0.f;
    for (int ic = qi * 64; ic < qi * 64 + 64; ++ic) {
        const float* ip = xp + ((size_t)(b * 256 + ic)) * 100 + y * 10 + x;
#pragma unroll
        for (int kh = 0; kh < 3; ++kh)
#pragma unroll
            for (int kw = 0; kw < 3; ++kw)
                acc = fmaf(w3[ic * 9 + kh * 3 + kw], ip[kh * 10 + kw], acc);
    }
    s[t] = acc;
    __syncthreads();
    if (t < 64) {
        float v = s[t] + s[t + 64] + s[t + 128] + s[t + 192];
#pragma unroll
        for (int off = 32; off >= 1; off >>= 1) v += __shfl_down(v, off);
        if (t == 0) out[4194304 + b] = v * (1.f / 64.f) + b3[0];
    }
}

// ---------------------------------------------------------------------------
extern "C" void kernel_launch(void* const* d_in, const int* in_sizes, int n_in,
                              void* d_out, int out_size, void* d_ws, size_t ws_size,
                              hipStream_t stream) {
    (void)in_sizes; (void)n_in; (void)out_size; (void)ws_size;
    const float* fqf = (const float*)d_in[0];  // fq_feats [9,4,512,32,32]
    const float* fsf = (const float*)d_in[1];  // fs_feats
    const float* fqi = (const float*)d_in[2];  // f_q [4,512,32,32]
    const float* fsi = (const float*)d_in[3];  // f_s
    const float* w1  = (const float*)d_in[4];
    const float* b1  = (const float*)d_in[5];
    const float* w2  = (const float*)d_in[6];
    const float* b2  = (const float*)d_in[7];
    const float* w3  = (const float*)d_in[8];
    const float* b3  = (const float*)d_in[9];
    float* out = (float*)d_out;

    float* W = (float*)d_ws;
    // [0 .. 4,194,304) f32: P01 fp16 corr partials (8.4M ush); aliased by
    //   attfq fp32 (2.1M, post-softmax)
    unsigned short* P01u = (unsigned short*)W;
    float* attfq = W;
    // [4,194,304 .. 6,553,600): attn fp16 padded (4.7M ush); aliased by w1p
    //   (ends 5,668,864), rpart [5,668,864..5,963,776), rq/rs
    //   [5,963,776..6,037,504) — all dead before k_softmax writes attn
    unsigned short* attn = (unsigned short*)(W + 4194304);
    unsigned short* w1p  = (unsigned short*)(W + 4194304);
    float* rpart = W + 5668864;    // [2 tz][4 kg][36864] ssq partials
    float* rq = W + 5963776;       // [36864] inverse norms (rfold out)
    float* rs = W + 6000640;       // [36864], contiguous with rq
    unsigned short* w2p  = (unsigned short*)(W + 4194304);
    // [6,553,600 .. 7,733,248): fs fp16 padded (2.36M ush)
    unsigned short* fsp = (unsigned short*)(W + 6553600);
    // [7,733,248 .. 8,257,536): x1 bf16 (1.05M ush)
    unsigned short* x1 = (unsigned short*)(W + 7733248);
    // [8,257,536 .. 8,359,936): xp fp32
    float* xp = W + 8257536;
    // [8,359,936 .. 17,797,120): fqb f16 tiles; aliased by conv partials P9
    //   (9,437,184 floats exactly) — P9 used only while fqb is dead
    unsigned short* fqb = (unsigned short*)(W + 8359936);
    float* P9 = W + 8359936;
    // [17,797,120 .. 27,234,304): fsb f16 tiles
    unsigned short* fsb = (unsigned short*)(W + 17797120);

    // conv1 phase (w1p in attn region, P9 in fqb region — both dead later)
    hipLaunchKernelGGL(k_w1pack,  dim3(1024),      dim3(256), 0, stream, w1, w1p);
    hipLaunchKernelGGL(k_conv1m,  dim3(16, 4, 9),  dim3(256), 0, stream, fqi, fsi, w1p, P9);
    hipLaunchKernelGGL(k_c1comb,  dim3(1024),      dim3(256), 0, stream, P9, b1, x1);
    hipLaunchKernelGGL(k_fspack,  dim3(256),       dim3(256), 0, stream, fsi, fsp);
    // attention path
    hipLaunchKernelGGL(k_prep,    dim3(8, 36, 8),  dim3(256), 0, stream, fqf, fsf, fqb, fsb, rpart);
    hipLaunchKernelGGL(k_rfold,   dim3(288),       dim3(256), 0, stream, rpart, rq);
    hipLaunchKernelGGL(k_corr2,   dim3(512),       dim3(256), 0, stream, fqb, fsb, rq, rs, P01u);
    hipLaunchKernelGGL(k_softmax, dim3(4096),      dim3(256), 0, stream, P01u, attn);
    hipLaunchKernelGGL(k_attfqm,  dim3(8, 8, 4),   dim3(256), 0, stream, fsp, attn, attfq);
    hipLaunchKernelGGL(k_out,     dim3(64, 4),     dim3(256), 0, stream, fqi, attfq, out);
    // conv tail (w2p in attn region, P9 in fqb region — dead after k_out/corr2)
    hipLaunchKernelGGL(k_w2pack,  dim3(256),       dim3(256), 0, stream, w2, w2p);
    hipLaunchKernelGGL(k_conv2m,  dim3(16, 4, 9),  dim3(256), 0, stream, x1, w2p, P9);
    hipLaunchKernelGGL(k_c2pool,  dim3(400),       dim3(256), 0, stream, P9, b2, xp);
    hipLaunchKernelGGL(k_conv3,   dim3(4),         dim3(256), 0, stream, xp, w3, b3, out);
}